// Round 12
// baseline (501.544 us; speedup 1.0000x reference)
//
#include <hip/hip_runtime.h>
#include <hip/hip_fp16.h>
#include <stdint.h>

#define B_   16
#define T_   30
#define NF   480       // frames = B*T
#define NN   2048      // nodes
#define EE   32768     // edges
#define EPS  1e-5f

typedef unsigned int u32;
typedef unsigned short u16;
typedef __attribute__((ext_vector_type(8))) short short8;   // 8 bf16 = 4 VGPR
typedef __attribute__((ext_vector_type(4))) float f32x4;    // MFMA C/D frag

// ---------- helpers ----------
__device__ __forceinline__ u16 f2bf(float f) {           // RNE f32->bf16
  u32 u = __float_as_uint(f);
  u32 r = u + 0x7FFFu + ((u >> 16) & 1u);
  return (u16)(r >> 16);
}
__device__ __forceinline__ u32 pack2bf(float a, float b) {
  return (u32)f2bf(a) | ((u32)f2bf(b) << 16);
}
__device__ __forceinline__ float bflo(u32 w) { return __uint_as_float(w << 16); }
__device__ __forceinline__ float bfhi(u32 w) { return __uint_as_float(w & 0xFFFF0000u); }
__device__ __forceinline__ u16 f2h(float f) { return __half_as_ushort(__float2half(f)); }
__device__ __forceinline__ float h2f(u16 h) { return __half2float(__ushort_as_half(h)); }
__device__ __forceinline__ u32 pack2h(float a, float b) {
  return (u32)f2h(a) | ((u32)f2h(b) << 16);
}

// =========================================================================
// kPre: sort node_ids -> perm; degrees; rank dsts by length (desc, exact
//       per-length buckets); JDS offsets; counting-sort edges into JDS
//       layout in LDS (src = ORIG x-row); coalesced stream-out.
// =========================================================================
#define KP_KEYS 0          // u32[2048] (dead before rec overlay)
#define KP_HIST 8192       // u32[256]  (scan scratch; dead before overlay)
#define KP_CUM  9216       // u32[256]
#define KP_CUR  10240      // u32[256]
#define KP_REC  0          // overlay u32[32768] = 131072 B
#define KP_DINV 131072     // f32[2048]
#define KP_CNT  139264     // u32[2048]
#define KP_PERM 147456     // u16[2048]
#define KP_RANK 151552     // u16[2048]
#define KP_OFF  155648     // u32[256]
#define KP_LDS  156672

__global__ __launch_bounds__(1024) void kPre(
    const int* __restrict__ ei, const float* __restrict__ ew, const int* __restrict__ nid,
    u32* __restrict__ recG, u32* __restrict__ metaG, float* __restrict__ dv2G,
    u32* __restrict__ offG)
{
  extern __shared__ unsigned char smem[];
  const int g = blockIdx.x, t = threadIdx.x;
  const int*   eig  = ei  + (size_t)g * 2 * EE;
  const float* ewg  = ew  + (size_t)g * EE;
  const int*   nidg = nid + (size_t)g * NN;

  u32*  keys = (u32*)(smem + KP_KEYS);
  u32*  hist = (u32*)(smem + KP_HIST);
  u32*  cum  = (u32*)(smem + KP_CUM);
  u32*  cur  = (u32*)(smem + KP_CUR);
  u32*  rec  = (u32*)(smem + KP_REC);
  float* dinv = (float*)(smem + KP_DINV);
  u32*  cnt  = (u32*)(smem + KP_CNT);
  u16*  perm = (u16*)(smem + KP_PERM);
  u16*  rank = (u16*)(smem + KP_RANK);
  u32*  off  = (u32*)(smem + KP_OFF);

  // keys (stable sort: key = nid<<11 | idx), init dinv/cnt
  keys[t]        = ((u32)nidg[t] << 11) | (u32)t;
  keys[t + 1024] = ((u32)nidg[t + 1024] << 11) | (u32)(t + 1024);
  dinv[t] = 1.0f; dinv[t + 1024] = 1.0f;
  cnt[t] = 0u; cnt[t + 1024] = 0u;
  __syncthreads();

  // bitonic sort, 1 pair/thread/pass
  for (int k = 2; k <= NN; k <<= 1) {
    for (int j = k >> 1; j > 0; j >>= 1) {
      int i = ((t & ~(j - 1)) << 1) | (t & (j - 1));
      int l = i | j;
      u32 x = keys[i], y = keys[l];
      bool up = ((i & k) == 0);
      if ((x > y) == up) { keys[i] = y; keys[l] = x; }
      __syncthreads();
    }
  }
  perm[2*t]   = (u16)(keys[2*t] & 2047u);
  perm[2*t+1] = (u16)(keys[2*t+1] & 2047u);

  // degree (self-loop weight 1) + per-dst edge count
  for (int e = t; e < EE; e += 1024) {
    int d = eig[EE + e];
    atomicAdd(&dinv[d], ewg[e]);
    atomicAdd(&cnt[d], 1u);
  }
  __syncthreads();
  dinv[2*t]   = rsqrtf(dinv[2*t]);
  dinv[2*t+1] = rsqrtf(dinv[2*t+1]);

  // ---- length histogram (256 buckets) ----
  if (t < 256) hist[t] = 0u;
  __syncthreads();
  for (int i = t; i < NN; i += 1024) {
    u32 L = cnt[i];
    atomicAdd(&hist[L < 255u ? L : 255u], 1u);
  }
  __syncthreads();
  if (t < 256) cum[t] = hist[t];
  __syncthreads();
  for (int o = 1; o < 256; o <<= 1) {
    u32 v = 0u;
    if (t < 256 && t >= o) v = cum[t - o];
    __syncthreads();
    if (t < 256) cum[t] += v;
    __syncthreads();
  }
  // cntgt[b] = #len > b ; cur = bucket start (descending order)
  if (t < 256) cur[t] = (u32)NN - cum[t];
  __syncthreads();
  // off = exclusive prefix of cntgt (reuse hist as scan buffer)
  if (t < 256) hist[t] = cur[t];
  __syncthreads();
  for (int o = 1; o < 256; o <<= 1) {
    u32 v = 0u;
    if (t < 256 && t >= o) v = hist[t - o];
    __syncthreads();
    if (t < 256) hist[t] += v;
    __syncthreads();
  }
  if (t < 256) {
    u32 ov = hist[t] - cur[t];
    off[t] = ov;
    offG[(size_t)g * 256 + t] = ov;
  }
  __syncthreads();

  // ---- rank assignment (desc length) ----
  for (int i = t; i < NN; i += 1024) {
    u32 L = cnt[i];
    u32 b = L < 255u ? L : 255u;
    u32 r = atomicAdd(&cur[b], 1u);
    rank[i] = (u16)r;
    metaG[(size_t)g * NN + r] = ((u32)perm[i] << 16) | (L & 0xFFFFu);
    float dv = dinv[i];
    dv2G[(size_t)g * NN + r] = dv * dv;
  }
  __syncthreads();
  // reset cnt as per-dst cursor
  cnt[t] = 0u; cnt[t + 1024] = 0u;
  __syncthreads();   // keys/hist/cum/cur dead -> rec overlays [0,131072)

  // ---- counting-sort edges into JDS: rec[off[k] + rank[d]] ----
  for (int e = t; e < EE; e += 1024) {
    int s = eig[e], d = eig[EE + e];
    float nrm = dinv[s] * ewg[e] * dinv[d];
    u32 k = atomicAdd(&cnt[d], 1u);
    u32 pos = off[k] + (u32)rank[d];
    rec[pos] = ((u32)perm[s] << 16) | (u32)f2h(nrm);   // src in ORIG x-row space
  }
  __syncthreads();

  // coalesced stream-out
  uint4* rg = (uint4*)(recG + (size_t)g * EE);
  const uint4* rl = (const uint4*)rec;
  for (int i = t; i < EE / 4; i += 1024) rg[i] = rl[i];
}

// =========================================================================
// kFuse v8: = v6 (4-wide phase-C record batching) + sched_barrier(0x20)
//   between per-row LDS-gather bodies.  r10/r11 spilled because the
//   scheduler hoisted all 16 uint4 LDS row-loads above their uses
//   (64 VGPRs of w_) at the compiler's 64-VGPR target; the barrier pins
//   one row's loads+FMAs at a time (mask 0x20: VMEM reads may still
//   cross, so the 4 global record loads stay in flight).
// =========================================================================
#define KF_H1   0        // A: xs f32[2048][8] (64KB); B/C: h1 f16[2048][32] (128KB)
#define KF_W1   131072   // f32[512]
#define KF_T1   133120   // f32[64]
#define KF_OFF  133376   // u32[256]
#define KF_LDS  134400

__global__ __launch_bounds__(1024) void kFuse(
    const float* __restrict__ x, const u32* __restrict__ recG,
    const u32* __restrict__ metaG, const float* __restrict__ dv2G,
    const u32* __restrict__ offG,
    const float* __restrict__ W1f, const float* __restrict__ t1f,
    u16* __restrict__ aggOut)
{
  extern __shared__ unsigned char smem[];
  float* xs  = (float*)smem;                  // phase A
  u16*  h1   = (u16*)smem;                    // phases B/C: [2048][32] f16
  float* W1s = (float*)(smem + KF_W1);
  float* t1s = (float*)(smem + KF_T1);
  u32*  offL = (u32*)(smem + KF_OFF);
  const int g = blockIdx.x, t = threadIdx.x;
  const u32* recf = recG + (size_t)g * EE;

  // stage x rows (orig order, coalesced) + constants
  {
    const float4* xg = (const float4*)(x + (size_t)g * NN * 8);
    for (int i = t; i < NN * 2; i += 1024) ((float4*)xs)[i] = xg[i];
  }
  if (t < 512) W1s[t] = W1f[t];
  if (t < 64) t1s[t] = t1f[t];
  if (t >= 512 && t < 768) offL[t - 512] = offG[(size_t)g * 256 + (t - 512)];

  // per-rank meta (rank-major, coalesced)
  u32 origA[2], lenA[2]; float dvA[2];
  #pragma unroll
  for (int it = 0; it < 2; ++it) {
    u32 r = (u32)(it * 1024 + t);
    u32 m = metaG[(size_t)g * NN + r];
    origA[it] = m >> 16; lenA[it] = m & 0xFFFFu;
    dvA[it] = dv2G[(size_t)g * NN + r];
  }
  __syncthreads();

  // ---- phase A: walk-1 in 8-dim x space, agg stays in registers ----
  float agg[2][8];
#define P1(RC) { u32 rc_ = (RC); u32 s_ = rc_ >> 16; \
    float nm_ = h2f((u16)(rc_ & 0xFFFFu)); \
    const float4* xp_ = (const float4*)(smem + (size_t)s_ * 32); \
    float4 a_ = xp_[0], b_ = xp_[1]; \
    ac0 += nm_*a_.x; ac1 += nm_*a_.y; ac2 += nm_*a_.z; ac3 += nm_*a_.w; \
    ac4 += nm_*b_.x; ac5 += nm_*b_.y; ac6 += nm_*b_.z; ac7 += nm_*b_.w; }
  #pragma unroll
  for (int it = 0; it < 2; ++it) {
    u32 r = (u32)(it * 1024 + t);
    float ac0=0,ac1=0,ac2=0,ac3=0,ac4=0,ac5=0,ac6=0,ac7=0;
    int len = (int)lenA[it];
    int j = 0;
    for (; j + 4 <= len; j += 4) {       // JDS: lane-contiguous rec reads
      u32 o0 = offL[j], o1 = offL[j+1], o2 = offL[j+2], o3 = offL[j+3];
      u32 q0 = recf[o0 + r], q1 = recf[o1 + r], q2 = recf[o2 + r], q3 = recf[o3 + r];
      P1(q0) P1(q1) P1(q2) P1(q3)
    }
    for (; j < len; ++j) { P1(recf[offL[j] + r]) }
    {  // self-loop (dv = dinv^2)
      const float4* xd = (const float4*)(smem + (size_t)origA[it] * 32);
      float4 a = xd[0], b = xd[1];
      float dv = dvA[it];
      ac0 += dv*a.x; ac1 += dv*a.y; ac2 += dv*a.z; ac3 += dv*a.w;
      ac4 += dv*b.x; ac5 += dv*b.y; ac6 += dv*b.z; ac7 += dv*b.w;
    }
    agg[it][0]=ac0; agg[it][1]=ac1; agg[it][2]=ac2; agg[it][3]=ac3;
    agg[it][4]=ac4; agg[it][5]=ac5; agg[it][6]=ac6; agg[it][7]=ac7;
  }
#undef P1

  // ---- 2 passes x 32 features ----
  for (int p = 0; p < 2; ++p) {
    __syncthreads();   // pass 0: xs dead; pass 1: previous h1 readers done

    // phase B: h1 slice (feats p*32..p*32+31) from registers, f16, swizzled
    #pragma unroll
    for (int it = 0; it < 2; ++it) {
      float z[32];
      #pragma unroll
      for (int f = 0; f < 32; ++f) z[f] = t1s[p * 32 + f];
      #pragma unroll
      for (int k = 0; k < 8; ++k) {
        float fk = agg[it][k];
        const float4* wr = (const float4*)(W1s + k * 64 + p * 32);
        #pragma unroll
        for (int q = 0; q < 8; ++q) {
          float4 w = wr[q];
          z[4*q]   += fk * w.x; z[4*q+1] += fk * w.y;
          z[4*q+2] += fk * w.z; z[4*q+3] += fk * w.w;
        }
      }
      u32 orig = origA[it];
      u32 sw = (orig >> 1) & 3u;
      uint4* hp = (uint4*)(h1 + (size_t)orig * 32);
      #pragma unroll
      for (int u = 0; u < 4; ++u) {
        int b = u * 8;
        uint4 v = make_uint4(
          pack2h(fmaxf(z[b],   0.f), fmaxf(z[b+1], 0.f)),
          pack2h(fmaxf(z[b+2], 0.f), fmaxf(z[b+3], 0.f)),
          pack2h(fmaxf(z[b+4], 0.f), fmaxf(z[b+5], 0.f)),
          pack2h(fmaxf(z[b+6], 0.f), fmaxf(z[b+7], 0.f)));
        hp[u ^ sw] = v;
      }
    }
    __syncthreads();

    // phase C: walk-2, 32 feats, acc in regs; 4 global records in flight,
    // LDS row bodies pinned one-at-a-time via sched_barrier(VMEM_READ-ok).
#define ROWACC(SRC, NM, OP) { u32 s_ = (SRC); float nm_ = (NM); \
    u32 sw_ = (s_ >> 1) & 3u; \
    const uint4* rp_ = (const uint4*)(h1 + (size_t)s_ * 32); \
    _Pragma("unroll") \
    for (int u = 0; u < 4; ++u) { \
      uint4 w_ = rp_[u ^ sw_]; \
      int b_ = u * 8; \
      acc[b_+0] OP nm_ * h2f((u16)(w_.x & 0xFFFFu)); \
      acc[b_+1] OP nm_ * h2f((u16)(w_.x >> 16)); \
      acc[b_+2] OP nm_ * h2f((u16)(w_.y & 0xFFFFu)); \
      acc[b_+3] OP nm_ * h2f((u16)(w_.y >> 16)); \
      acc[b_+4] OP nm_ * h2f((u16)(w_.z & 0xFFFFu)); \
      acc[b_+5] OP nm_ * h2f((u16)(w_.z >> 16)); \
      acc[b_+6] OP nm_ * h2f((u16)(w_.w & 0xFFFFu)); \
      acc[b_+7] OP nm_ * h2f((u16)(w_.w >> 16)); \
    } }

    for (int it = 0; it < 2; ++it) {
      u32 r = (u32)(it * 1024 + t);
      float acc[32];
      ROWACC(origA[it], dvA[it], =)      // self-loop initializes acc
      int len = (int)lenA[it];
      int j = 0;
      for (; j + 4 <= len; j += 4) {     // 4 offL + 4 global loads in flight
        u32 o0 = offL[j], o1 = offL[j+1], o2 = offL[j+2], o3 = offL[j+3];
        u32 q0 = recf[o0 + r], q1 = recf[o1 + r], q2 = recf[o2 + r], q3 = recf[o3 + r];
        ROWACC(q0 >> 16, h2f((u16)(q0 & 0xFFFFu)), +=)
        __builtin_amdgcn_sched_barrier(0x20);   // only VMEM reads may cross
        ROWACC(q1 >> 16, h2f((u16)(q1 & 0xFFFFu)), +=)
        __builtin_amdgcn_sched_barrier(0x20);
        ROWACC(q2 >> 16, h2f((u16)(q2 & 0xFFFFu)), +=)
        __builtin_amdgcn_sched_barrier(0x20);
        ROWACC(q3 >> 16, h2f((u16)(q3 & 0xFFFFu)), +=)
        __builtin_amdgcn_sched_barrier(0x20);
      }
      for (; j < len; ++j) {
        u32 q = recf[offL[j] + r];
        ROWACC(q >> 16, h2f((u16)(q & 0xFFFFu)), +=)
      }
      // pass p -> unit-planes p*4..p*4+3 (feats p*32+u*8..+7), 16B/lane
      #pragma unroll
      for (int u = 0; u < 4; ++u) {
        int b = u * 8;
        uint4 o = make_uint4(
          pack2bf(acc[b],   acc[b+1]), pack2bf(acc[b+2], acc[b+3]),
          pack2bf(acc[b+4], acc[b+5]), pack2bf(acc[b+6], acc[b+7]));
        *((uint4*)aggOut + ((size_t)(g * 8 + p * 4 + u)) * NN + r) = o;
      }
    }
#undef ROWACC
  }
}

// =========================================================================
// kW2p: one-shot prep — W2 -> bf16 W2bT[f][k] + BN2 fold; W1f = W1*s1, t1f.
// =========================================================================
__global__ void kW2p(const float* __restrict__ W2, const float* __restrict__ b2,
                     const float* __restrict__ g2, const float* __restrict__ be2,
                     const float* __restrict__ m2, const float* __restrict__ v2,
                     const float* __restrict__ W1, const float* __restrict__ b1,
                     const float* __restrict__ g1, const float* __restrict__ be1,
                     const float* __restrict__ m1, const float* __restrict__ v1,
                     u16* __restrict__ W2bT, float* __restrict__ scG, float* __restrict__ tcG,
                     float* __restrict__ W1f, float* __restrict__ t1f)
{
  const int t = threadIdx.x;    // 256
  for (int i = t; i < 4096; i += 256) {
    int f = i >> 6, k = i & 63;
    W2bT[i] = f2bf(W2[k * 64 + f]);
  }
  for (int i = t; i < 512; i += 256) {
    int f = i & 63;
    float sc = g1[f] * rsqrtf(v1[f] + EPS);
    W1f[i] = W1[i] * sc;
  }
  if (t < 64) {
    float sc2 = g2[t] * rsqrtf(v2[t] + EPS);
    scG[t] = sc2;
    tcG[t] = (b2[t] - m2[t]) * sc2 + be2[t];
    float sc1 = g1[t] * rsqrtf(v1[t] + EPS);
    t1f[t] = (b1[t] - m1[t]) * sc1 + be1[t];
  }
}

// =========================================================================
// kB: MFMA GEMM  C = agg2[2048x64](bf16, 8 unit-planes) @ W2(bf16), fused
//     BN+ReLU+mean.  A/B frags share one k-slot bijection.
// =========================================================================
__global__ __launch_bounds__(512) void kB(
    const u16* __restrict__ agg, const u16* __restrict__ W2bT,
    const float* __restrict__ scG, const float* __restrict__ tcG,
    float* __restrict__ frames)
{
  __shared__ u16 W2s[4096];          // bf16 [f=64][k=64]
  __shared__ float part[8][64];
  const int g = blockIdx.x, tid = threadIdx.x;
  const int l = tid & 63, w = tid >> 6;
  const int lc = l & 15, lg = l >> 4;          // frag col / k-group

  ((uint4*)W2s)[tid] = ((const uint4*)W2bT)[tid];
  __syncthreads();

  short8 bfr[4][2];
  float scv[4], tcv[4];
  #pragma unroll
  for (int ct = 0; ct < 4; ++ct) {
    #pragma unroll
    for (int kt = 0; kt < 2; ++kt)
      bfr[ct][kt] = *(const short8*)(W2s + (ct * 16 + lc) * 64 + kt * 32 + lg * 8);
    scv[ct] = scG[ct * 16 + lc];
    tcv[ct] = tcG[ct * 16 + lc];
  }

  const u16* base = agg + (size_t)g * (8 * NN * 8);   // 8 unit-planes x NN x 8 u16
  float fs0 = 0.f, fs1 = 0.f, fs2 = 0.f, fs3 = 0.f;

  for (int rti = 0; rti < 16; ++rti) {
    int arow = (w * 16 + rti) * 16 + lc;
    short8 a0 = *(const short8*)(base + ((size_t)(0 * 4 + lg) * NN + arow) * 8);
    short8 a1 = *(const short8*)(base + ((size_t)(1 * 4 + lg) * NN + arow) * 8);
#define CTILE(CT, FS) { \
    f32x4 acc = {0.f, 0.f, 0.f, 0.f}; \
    acc = __builtin_amdgcn_mfma_f32_16x16x32_bf16(a0, bfr[CT][0], acc, 0, 0, 0); \
    acc = __builtin_amdgcn_mfma_f32_16x16x32_bf16(a1, bfr[CT][1], acc, 0, 0, 0); \
    float s_ = fmaxf(acc[0] * scv[CT] + tcv[CT], 0.f) \
             + fmaxf(acc[1] * scv[CT] + tcv[CT], 0.f) \
             + fmaxf(acc[2] * scv[CT] + tcv[CT], 0.f) \
             + fmaxf(acc[3] * scv[CT] + tcv[CT], 0.f); \
    s_ += __shfl_xor(s_, 16); \
    s_ += __shfl_xor(s_, 32); \
    FS += s_; }
    CTILE(0, fs0) CTILE(1, fs1) CTILE(2, fs2) CTILE(3, fs3)
#undef CTILE
  }
  if (l < 16) {
    part[w][ 0 + l] = fs0;
    part[w][16 + l] = fs1;
    part[w][32 + l] = fs2;
    part[w][48 + l] = fs3;
  }
  __syncthreads();
  if (tid < 64) {
    float s = 0.f;
    #pragma unroll
    for (int q = 0; q < 8; ++q) s += part[q][tid];
    frames[g * 64 + tid] = s * (1.0f / 2048.0f);
  }
}

// =========================================================================
// kC: GRU over T=30 + classifier; one block per batch element
// =========================================================================
__global__ __launch_bounds__(384, 2) void kC(
    const float* __restrict__ frames,
    const float* __restrict__ Wih, const float* __restrict__ Whh,
    const float* __restrict__ bih, const float* __restrict__ bhh,
    const float* __restrict__ Wc1, const float* __restrict__ bc1,
    const float* __restrict__ Wc2, const float* __restrict__ bc2,
    float* __restrict__ out)
{
  const int b = blockIdx.x;
  const int j = threadIdx.x;     // 384 = 3*TEMP gate rows
  __shared__ float xt[64], h[128], GI[384], GH[384], hid[64];
  float wih[64], whh[128];
  const float4* wi4 = (const float4*)(Wih + (size_t)j * 64);
  #pragma unroll
  for (int q = 0; q < 16; ++q) { float4 v = wi4[q]; wih[4*q]=v.x; wih[4*q+1]=v.y; wih[4*q+2]=v.z; wih[4*q+3]=v.w; }
  const float4* wh4 = (const float4*)(Whh + (size_t)j * 128);
  #pragma unroll
  for (int q = 0; q < 32; ++q) { float4 v = wh4[q]; whh[4*q]=v.x; whh[4*q+1]=v.y; whh[4*q+2]=v.z; whh[4*q+3]=v.w; }
  float bi = bih[j], bh = bhh[j];
  if (j < 128) h[j] = 0.f;
  __syncthreads();
  for (int t = 0; t < T_; ++t) {
    if (j < 64) xt[j] = frames[((size_t)b * T_ + t) * 64 + j];
    __syncthreads();
    float gi = bi, gh = bh;
    #pragma unroll
    for (int k = 0; k < 64; ++k) gi += xt[k] * wih[k];
    #pragma unroll
    for (int k = 0; k < 128; ++k) gh += h[k] * whh[k];
    GI[j] = gi; GH[j] = gh;
    __syncthreads();
    if (j < 128) {
      float r = 1.f / (1.f + __expf(-(GI[j] + GH[j])));
      float z = 1.f / (1.f + __expf(-(GI[128 + j] + GH[128 + j])));
      float n = tanhf(GI[256 + j] + r * GH[256 + j]);
      h[j] = (1.f - z) * n + z * h[j];
    }
    __syncthreads();
  }
  if (j < 64) {
    float a = bc1[j];
    #pragma unroll 4
    for (int k = 0; k < 128; ++k) a += h[k] * Wc1[k * 64 + j];
    hid[j] = fmaxf(a, 0.f);
  }
  __syncthreads();
  if (j < 2) {
    float o = bc2[j];
    #pragma unroll
    for (int k = 0; k < 64; ++k) o += hid[k] * Wc2[k * 2 + j];
    out[b * 2 + j] = o;
  }
}

// ---------- launch ----------
extern "C" void kernel_launch(void* const* d_in, const int* in_sizes, int n_in,
                              void* d_out, int out_size, void* d_ws, size_t ws_size,
                              hipStream_t stream) {
  const float* x   = (const float*)d_in[0];
  const int*   ei  = (const int*)d_in[1];
  const float* ew  = (const float*)d_in[2];
  const int*   nid = (const int*)d_in[3];
  const float* W1  = (const float*)d_in[4];
  const float* b1  = (const float*)d_in[5];
  const float* W2  = (const float*)d_in[6];
  const float* b2  = (const float*)d_in[7];
  const float* g1  = (const float*)d_in[8];
  const float* be1 = (const float*)d_in[9];
  const float* m1  = (const float*)d_in[10];
  const float* v1  = (const float*)d_in[11];
  const float* g2  = (const float*)d_in[12];
  const float* be2 = (const float*)d_in[13];
  const float* m2  = (const float*)d_in[14];
  const float* v2  = (const float*)d_in[15];
  const float* Wih = (const float*)d_in[16];
  const float* Whh = (const float*)d_in[17];
  const float* bih = (const float*)d_in[18];
  const float* bhh = (const float*)d_in[19];
  const float* Wc1 = (const float*)d_in[20];
  const float* bc1 = (const float*)d_in[21];
  const float* Wc2 = (const float*)d_in[22];
  const float* bc2 = (const float*)d_in[23];
  float* out = (float*)d_out;

  // workspace layout (bytes), total ~197.2MB (< proven 198.7MB)
  const size_t REC_OFF   = 0;                    // 62,914,560
  const size_t PL_OFF    = 62914560;             // agg2 8 unit-planes bf16: 125,829,120
  const size_t META_OFF  = 188743680;            // u32[480*2048] = 3,932,160
  const size_t DV2_OFF   = 192675840;            // f32[480*2048] = 3,932,160
  const size_t OFF_OFF   = 196608000;            // u32[480*256] = 491,520
  const size_t PREP_OFF  = 197099520;            // W2bT 8192 | scG 256 | tcG 256 | W1f 2048 | t1f 256
  const size_t FR_OFF    = 197110528;            // 122,880
  if (ws_size < (size_t)197233408) return;

  u32*   rec   = (u32*)((char*)d_ws + REC_OFF);
  u16*   agg2  = (u16*)((char*)d_ws + PL_OFF);
  u32*   metaG = (u32*)((char*)d_ws + META_OFF);
  float* dv2G  = (float*)((char*)d_ws + DV2_OFF);
  u32*   offG  = (u32*)((char*)d_ws + OFF_OFF);
  u16*   W2bT  = (u16*)((char*)d_ws + PREP_OFF);
  float* scG   = (float*)((char*)d_ws + PREP_OFF + 8192);
  float* tcG   = (float*)((char*)d_ws + PREP_OFF + 8448);
  float* W1f   = (float*)((char*)d_ws + PREP_OFF + 8704);
  float* t1f   = (float*)((char*)d_ws + PREP_OFF + 10752);
  float* frm   = (float*)((char*)d_ws + FR_OFF);

  hipFuncSetAttribute((const void*)kPre,  hipFuncAttributeMaxDynamicSharedMemorySize, KP_LDS);
  hipFuncSetAttribute((const void*)kFuse, hipFuncAttributeMaxDynamicSharedMemorySize, KF_LDS);

  kW2p<<<1, 256, 0, stream>>>(W2, b2, g2, be2, m2, v2,
                              W1, b1, g1, be1, m1, v1,
                              W2bT, scG, tcG, W1f, t1f);
  kPre<<<NF, 1024, KP_LDS, stream>>>(ei, ew, nid, rec, metaG, dv2G, offG);
  kFuse<<<NF, 1024, KF_LDS, stream>>>(x, rec, metaG, dv2G, offG, W1f, t1f, agg2);
  kB<<<NF, 512, 0, stream>>>(agg2, W2bT, scG, tcG, frm);
  kC<<<B_, 384, 0, stream>>>(frm, Wih, Whh, bih, bhh, Wc1, bc1, Wc2, bc2, out);
}

// Round 13
// 462.586 us; speedup vs baseline: 1.0842x; 1.0842x over previous
//
#include <hip/hip_runtime.h>
#include <hip/hip_fp16.h>
#include <stdint.h>

#define B_   16
#define T_   30
#define NF   480       // frames = B*T
#define NN   2048      // nodes
#define EE   32768     // edges
#define EPS  1e-5f

typedef unsigned int u32;
typedef unsigned short u16;
typedef __attribute__((ext_vector_type(8))) short short8;   // 8 bf16 = 4 VGPR
typedef __attribute__((ext_vector_type(4))) float f32x4;    // MFMA C/D frag

// ---------- helpers ----------
__device__ __forceinline__ u16 f2bf(float f) {           // RNE f32->bf16
  u32 u = __float_as_uint(f);
  u32 r = u + 0x7FFFu + ((u >> 16) & 1u);
  return (u16)(r >> 16);
}
__device__ __forceinline__ u32 pack2bf(float a, float b) {
  return (u32)f2bf(a) | ((u32)f2bf(b) << 16);
}
__device__ __forceinline__ u16 f2h(float f) { return __half_as_ushort(__float2half(f)); }
__device__ __forceinline__ float h2f(u16 h) { return __half2float(__ushort_as_half(h)); }
__device__ __forceinline__ u32 pack2h(float a, float b) {
  return (u32)f2h(a) | ((u32)f2h(b) << 16);
}

// agg2 frame region (u16 units): 8 planes x NN x 8 = 131072 u16 = 256KB.
// kMeta stashes per-NODE meta at its head (dead until kFuse reads then
// overwrites): nodeP u32[2048] @ u16-off 0..4095, dinvN f16[2048] @ 4096.
#define AGG_FRAME_U16 131072
#define STASH_DINV_U16 4096

// =========================================================================
// kMeta: sort node_ids -> perm; degrees; rank dsts by length (desc);
//        JDS offsets; exports metaR (by rank), nodeP+dinvN (stash), offG.
//        35KB LDS -> 2 blocks/CU (32 waves).  Block 0 also does W-prep.
// =========================================================================
#define KM_KEYS 0        // u32[2048]
#define KM_DEG  8192     // f32[2048]
#define KM_CNT  16384    // u32[2048]
#define KM_PR   24576    // u32[2048]  perm<<16 | rank
#define KM_HIST 32768    // u32[256]
#define KM_CUM  33792    // u32[256]
#define KM_CUR  34816    // u32[256]
#define KM_LDS  35840

__global__ __launch_bounds__(1024) void kMeta(
    const int* __restrict__ ei, const float* __restrict__ ew, const int* __restrict__ nid,
    u32* __restrict__ metaR, u32* __restrict__ offG, u16* __restrict__ aggStash,
    const float* __restrict__ W2, const float* __restrict__ b2,
    const float* __restrict__ g2, const float* __restrict__ be2,
    const float* __restrict__ m2, const float* __restrict__ v2,
    const float* __restrict__ W1, const float* __restrict__ b1,
    const float* __restrict__ g1, const float* __restrict__ be1,
    const float* __restrict__ m1, const float* __restrict__ v1,
    u16* __restrict__ W2bT, float* __restrict__ scG, float* __restrict__ tcG,
    float* __restrict__ W1f, float* __restrict__ t1f)
{
  extern __shared__ unsigned char smem[];
  const int g = blockIdx.x, t = threadIdx.x;
  const int*   eig  = ei  + (size_t)g * 2 * EE;
  const float* ewg  = ew  + (size_t)g * EE;
  const int*   nidg = nid + (size_t)g * NN;

  u32*  keys = (u32*)(smem + KM_KEYS);
  float* deg = (float*)(smem + KM_DEG);
  u32*  cnt  = (u32*)(smem + KM_CNT);
  u32*  pr   = (u32*)(smem + KM_PR);
  u32*  hist = (u32*)(smem + KM_HIST);
  u32*  cum  = (u32*)(smem + KM_CUM);
  u32*  cur  = (u32*)(smem + KM_CUR);

  u32*  npG  = (u32*)(aggStash + (size_t)g * AGG_FRAME_U16);       // nodeP stash
  u16*  dvG  = aggStash + (size_t)g * AGG_FRAME_U16 + STASH_DINV_U16;

  // keys (stable sort: key = nid<<11 | idx), init
  keys[t]        = ((u32)nidg[t] << 11) | (u32)t;
  keys[t + 1024] = ((u32)nidg[t + 1024] << 11) | (u32)(t + 1024);
  deg[t] = 1.0f; deg[t + 1024] = 1.0f;
  cnt[t] = 0u; cnt[t + 1024] = 0u;
  __syncthreads();

  // bitonic sort, 1 pair/thread/pass
  for (int k = 2; k <= NN; k <<= 1) {
    for (int j = k >> 1; j > 0; j >>= 1) {
      int i = ((t & ~(j - 1)) << 1) | (t & (j - 1));
      int l = i | j;
      u32 x = keys[i], y = keys[l];
      bool up = ((i & k) == 0);
      if ((x > y) == up) { keys[i] = y; keys[l] = x; }
      __syncthreads();
    }
  }
  pr[2*t]   = (keys[2*t]   & 2047u) << 16;   // node i's x-row = perm[i]
  pr[2*t+1] = (keys[2*t+1] & 2047u) << 16;

  // degree (self-loop weight 1) + per-dst edge count
  for (int e = t; e < EE; e += 1024) {
    int d = eig[EE + e];
    atomicAdd(&deg[d], ewg[e]);
    atomicAdd(&cnt[d], 1u);
  }
  __syncthreads();
  {
    float d0 = rsqrtf(deg[2*t]), d1 = rsqrtf(deg[2*t+1]);
    dvG[2*t] = f2h(d0); dvG[2*t+1] = f2h(d1);   // f16 dinv by node (stash)
  }

  // ---- length histogram (256 buckets) ----
  if (t < 256) hist[t] = 0u;
  __syncthreads();
  for (int i = t; i < NN; i += 1024) {
    u32 L = cnt[i];
    atomicAdd(&hist[L < 255u ? L : 255u], 1u);
  }
  __syncthreads();
  if (t < 256) cum[t] = hist[t];
  __syncthreads();
  for (int o = 1; o < 256; o <<= 1) {
    u32 v = 0u;
    if (t < 256 && t >= o) v = cum[t - o];
    __syncthreads();
    if (t < 256) cum[t] += v;
    __syncthreads();
  }
  if (t < 256) cur[t] = (u32)NN - cum[t];   // bucket start (desc order)
  __syncthreads();
  if (t < 256) hist[t] = cur[t];            // scan buffer for off
  __syncthreads();
  for (int o = 1; o < 256; o <<= 1) {
    u32 v = 0u;
    if (t < 256 && t >= o) v = hist[t - o];
    __syncthreads();
    if (t < 256) hist[t] += v;
    __syncthreads();
  }
  if (t < 256) offG[(size_t)g * 256 + t] = hist[t] - cur[t];   // JDS offsets
  __syncthreads();

  // ---- rank assignment (desc length) ----
  for (int i = t; i < NN; i += 1024) {
    u32 L = cnt[i];
    u32 b = L < 255u ? L : 255u;
    u32 r = atomicAdd(&cur[b], 1u);
    pr[i] |= r;
    metaR[(size_t)g * NN + r] = (pr[i] & 0xFFFF0000u) | (L & 0xFFFFu);
  }
  __syncthreads();
  // export nodeP (perm<<16|rank), coalesced
  npG[2*t]   = pr[2*t];
  npG[2*t+1] = pr[2*t+1];

  // ---- block 0: fold in W-prep (was kW2p) ----
  if (g == 0) {
    for (int i = t; i < 4096; i += 1024) {
      int f = i >> 6, k = i & 63;
      W2bT[i] = f2bf(W2[k * 64 + f]);
    }
    if (t < 512) {
      int f = t & 63;
      float sc = g1[f] * rsqrtf(v1[f] + EPS);
      W1f[t] = W1[t] * sc;
    }
    if (t < 64) {
      float sc2 = g2[t] * rsqrtf(v2[t] + EPS);
      scG[t] = sc2;
      tcG[t] = (b2[t] - m2[t]) * sc2 + be2[t];
      float sc1 = g1[t] * rsqrtf(v1[t] + EPS);
      t1f[t] = (b1[t] - m1[t]) * sc1 + be1[t];
    }
  }
}

// =========================================================================
// kScatter: counting-sort edges into JDS rec in LDS; coalesced stream-out.
//   Reads nodeP/dinvN from the agg2-region stash (written by kMeta).
// =========================================================================
#define KS_REC  0        // u32[32768] = 131072
#define KS_CNT  131072   // u32[2048]
#define KS_PR   139264   // u32[2048]
#define KS_DINV 147456   // u16[2048]
#define KS_OFF  151552   // u32[256]
#define KS_LDS  152576

__global__ __launch_bounds__(1024) void kScatter(
    const int* __restrict__ ei, const float* __restrict__ ew,
    const u32* __restrict__ offG, const u16* __restrict__ aggStash,
    u32* __restrict__ recG)
{
  extern __shared__ unsigned char smem[];
  const int g = blockIdx.x, t = threadIdx.x;
  const int*   eig = ei + (size_t)g * 2 * EE;
  const float* ewg = ew + (size_t)g * EE;

  u32* rec   = (u32*)(smem + KS_REC);
  u32* cnt   = (u32*)(smem + KS_CNT);
  u32* prL   = (u32*)(smem + KS_PR);
  u16* dinvL = (u16*)(smem + KS_DINV);
  u32* off   = (u32*)(smem + KS_OFF);

  const u32* npG = (const u32*)(aggStash + (size_t)g * AGG_FRAME_U16);
  const u16* dvG = aggStash + (size_t)g * AGG_FRAME_U16 + STASH_DINV_U16;

  prL[2*t] = npG[2*t]; prL[2*t+1] = npG[2*t+1];
  dinvL[2*t] = dvG[2*t]; dinvL[2*t+1] = dvG[2*t+1];
  cnt[t] = 0u; cnt[t + 1024] = 0u;
  if (t < 256) off[t] = offG[(size_t)g * 256 + t];
  __syncthreads();

  for (int e = t; e < EE; e += 1024) {
    int s = eig[e], d = eig[EE + e];
    float nrm = h2f(dinvL[s]) * ewg[e] * h2f(dinvL[d]);
    u32 k = atomicAdd(&cnt[d], 1u);
    u32 pos = off[k] + (prL[d] & 0xFFFFu);
    rec[pos] = (prL[s] & 0xFFFF0000u) | (u32)f2h(nrm);   // src in ORIG x-row space
  }
  __syncthreads();

  uint4* rg = (uint4*)(recG + (size_t)g * EE);
  const uint4* rl = (const uint4*)rec;
  for (int i = t; i < EE / 4; i += 1024) rg[i] = rl[i];
}

// =========================================================================
// kFuse (r9 form): thread-per-rank JDS walks; h1 f16[2048][32] in LDS,
//   2 passes x 32 feats; phase C 1-wide (the proven-best variant).
//   dv2 now from f16 dinv stash (squared in f32).
// =========================================================================
#define KF_H1   0        // A: xs f32[2048][8] (64KB); B/C: h1 f16[2048][32] (128KB)
#define KF_W1   131072   // f32[512]
#define KF_T1   133120   // f32[64]
#define KF_OFF  133376   // u32[256]
#define KF_LDS  134400

__global__ __launch_bounds__(1024) void kFuse(
    const float* __restrict__ x, const u32* __restrict__ recG,
    const u32* __restrict__ metaR, const u32* __restrict__ offG,
    const float* __restrict__ W1f, const float* __restrict__ t1f,
    u16* __restrict__ aggOut)
{
  extern __shared__ unsigned char smem[];
  float* xs  = (float*)smem;                  // phase A
  u16*  h1   = (u16*)smem;                    // phases B/C: [2048][32] f16
  float* W1s = (float*)(smem + KF_W1);
  float* t1s = (float*)(smem + KF_T1);
  u32*  offL = (u32*)(smem + KF_OFF);
  const int g = blockIdx.x, t = threadIdx.x;
  const u32* recf = recG + (size_t)g * EE;
  const u16* dvN  = aggOut + (size_t)g * AGG_FRAME_U16 + STASH_DINV_U16;

  // stage x rows (orig order, coalesced) + constants
  {
    const float4* xg = (const float4*)(x + (size_t)g * NN * 8);
    for (int i = t; i < NN * 2; i += 1024) ((float4*)xs)[i] = xg[i];
  }
  if (t < 512) W1s[t] = W1f[t];
  if (t < 64) t1s[t] = t1f[t];
  if (t >= 512 && t < 768) offL[t - 512] = offG[(size_t)g * 256 + (t - 512)];

  // per-rank meta; dinv from stash (MUST read before any agg2 write)
  u32 origA[2], lenA[2]; float dvA[2];
  #pragma unroll
  for (int it = 0; it < 2; ++it) {
    u32 r = (u32)(it * 1024 + t);
    u32 m = metaR[(size_t)g * NN + r];
    origA[it] = m >> 16; lenA[it] = m & 0xFFFFu;
    float dv = h2f(dvN[origA[it]]);
    dvA[it] = dv * dv;
  }
  __syncthreads();

  // ---- phase A: walk-1 in 8-dim x space, agg stays in registers ----
  float agg[2][8];
#define P1(RC) { u32 rc_ = (RC); u32 s_ = rc_ >> 16; \
    float nm_ = h2f((u16)(rc_ & 0xFFFFu)); \
    const float4* xp_ = (const float4*)(smem + (size_t)s_ * 32); \
    float4 a_ = xp_[0], b_ = xp_[1]; \
    ac0 += nm_*a_.x; ac1 += nm_*a_.y; ac2 += nm_*a_.z; ac3 += nm_*a_.w; \
    ac4 += nm_*b_.x; ac5 += nm_*b_.y; ac6 += nm_*b_.z; ac7 += nm_*b_.w; }
  #pragma unroll
  for (int it = 0; it < 2; ++it) {
    u32 r = (u32)(it * 1024 + t);
    float ac0=0,ac1=0,ac2=0,ac3=0,ac4=0,ac5=0,ac6=0,ac7=0;
    int len = (int)lenA[it];
    int j = 0;
    for (; j + 4 <= len; j += 4) {       // JDS: lane-contiguous rec reads
      u32 o0 = offL[j], o1 = offL[j+1], o2 = offL[j+2], o3 = offL[j+3];
      u32 q0 = recf[o0 + r], q1 = recf[o1 + r], q2 = recf[o2 + r], q3 = recf[o3 + r];
      P1(q0) P1(q1) P1(q2) P1(q3)
    }
    for (; j < len; ++j) { P1(recf[offL[j] + r]) }
    {  // self-loop (dv = dinv^2)
      const float4* xd = (const float4*)(smem + (size_t)origA[it] * 32);
      float4 a = xd[0], b = xd[1];
      float dv = dvA[it];
      ac0 += dv*a.x; ac1 += dv*a.y; ac2 += dv*a.z; ac3 += dv*a.w;
      ac4 += dv*b.x; ac5 += dv*b.y; ac6 += dv*b.z; ac7 += dv*b.w;
    }
    agg[it][0]=ac0; agg[it][1]=ac1; agg[it][2]=ac2; agg[it][3]=ac3;
    agg[it][4]=ac4; agg[it][5]=ac5; agg[it][6]=ac6; agg[it][7]=ac7;
  }
#undef P1

  // ---- 2 passes x 32 features ----
  for (int p = 0; p < 2; ++p) {
    __syncthreads();   // pass 0: xs dead; pass 1: previous h1 readers done

    // phase B: h1 slice (feats p*32..p*32+31) from registers, f16, swizzled
    #pragma unroll
    for (int it = 0; it < 2; ++it) {
      float z[32];
      #pragma unroll
      for (int f = 0; f < 32; ++f) z[f] = t1s[p * 32 + f];
      #pragma unroll
      for (int k = 0; k < 8; ++k) {
        float fk = agg[it][k];
        const float4* wr = (const float4*)(W1s + k * 64 + p * 32);
        #pragma unroll
        for (int q = 0; q < 8; ++q) {
          float4 w = wr[q];
          z[4*q]   += fk * w.x; z[4*q+1] += fk * w.y;
          z[4*q+2] += fk * w.z; z[4*q+3] += fk * w.w;
        }
      }
      u32 orig = origA[it];
      u32 sw = (orig >> 1) & 3u;
      uint4* hp = (uint4*)(h1 + (size_t)orig * 32);
      #pragma unroll
      for (int u = 0; u < 4; ++u) {
        int b = u * 8;
        uint4 v = make_uint4(
          pack2h(fmaxf(z[b],   0.f), fmaxf(z[b+1], 0.f)),
          pack2h(fmaxf(z[b+2], 0.f), fmaxf(z[b+3], 0.f)),
          pack2h(fmaxf(z[b+4], 0.f), fmaxf(z[b+5], 0.f)),
          pack2h(fmaxf(z[b+6], 0.f), fmaxf(z[b+7], 0.f)));
        hp[u ^ sw] = v;
      }
    }
    __syncthreads();

    // phase C: walk-2, 32 feats, acc in regs (1-wide: r9 proven form)
#define ROWACC(SRC, NM, OP) { u32 s_ = (SRC); float nm_ = (NM); \
    u32 sw_ = (s_ >> 1) & 3u; \
    const uint4* rp_ = (const uint4*)(h1 + (size_t)s_ * 32); \
    _Pragma("unroll") \
    for (int u = 0; u < 4; ++u) { \
      uint4 w_ = rp_[u ^ sw_]; \
      int b_ = u * 8; \
      acc[b_+0] OP nm_ * h2f((u16)(w_.x & 0xFFFFu)); \
      acc[b_+1] OP nm_ * h2f((u16)(w_.x >> 16)); \
      acc[b_+2] OP nm_ * h2f((u16)(w_.y & 0xFFFFu)); \
      acc[b_+3] OP nm_ * h2f((u16)(w_.y >> 16)); \
      acc[b_+4] OP nm_ * h2f((u16)(w_.z & 0xFFFFu)); \
      acc[b_+5] OP nm_ * h2f((u16)(w_.z >> 16)); \
      acc[b_+6] OP nm_ * h2f((u16)(w_.w & 0xFFFFu)); \
      acc[b_+7] OP nm_ * h2f((u16)(w_.w >> 16)); \
    } }

    for (int it = 0; it < 2; ++it) {
      u32 r = (u32)(it * 1024 + t);
      float acc[32];
      ROWACC(origA[it], dvA[it], =)      // self-loop initializes acc
      int len = (int)lenA[it];
      for (int j = 0; j < len; ++j) {
        u32 q = recf[offL[j] + r];
        ROWACC(q >> 16, h2f((u16)(q & 0xFFFFu)), +=)
      }
      // pass p -> unit-planes p*4..p*4+3 (feats p*32+u*8..+7), 16B/lane
      #pragma unroll
      for (int u = 0; u < 4; ++u) {
        int b = u * 8;
        uint4 o = make_uint4(
          pack2bf(acc[b],   acc[b+1]), pack2bf(acc[b+2], acc[b+3]),
          pack2bf(acc[b+4], acc[b+5]), pack2bf(acc[b+6], acc[b+7]));
        *((uint4*)aggOut + ((size_t)(g * 8 + p * 4 + u)) * NN + r) = o;
      }
    }
#undef ROWACC
  }
}

// =========================================================================
// kB: MFMA GEMM  C = agg2[2048x64](bf16, 8 unit-planes) @ W2(bf16), fused
//     BN+ReLU+mean.  A/B frags share one k-slot bijection.
// =========================================================================
__global__ __launch_bounds__(512) void kB(
    const u16* __restrict__ agg, const u16* __restrict__ W2bT,
    const float* __restrict__ scG, const float* __restrict__ tcG,
    float* __restrict__ frames)
{
  __shared__ u16 W2s[4096];          // bf16 [f=64][k=64]
  __shared__ float part[8][64];
  const int g = blockIdx.x, tid = threadIdx.x;
  const int l = tid & 63, w = tid >> 6;
  const int lc = l & 15, lg = l >> 4;          // frag col / k-group

  ((uint4*)W2s)[tid] = ((const uint4*)W2bT)[tid];
  __syncthreads();

  short8 bfr[4][2];
  float scv[4], tcv[4];
  #pragma unroll
  for (int ct = 0; ct < 4; ++ct) {
    #pragma unroll
    for (int kt = 0; kt < 2; ++kt)
      bfr[ct][kt] = *(const short8*)(W2s + (ct * 16 + lc) * 64 + kt * 32 + lg * 8);
    scv[ct] = scG[ct * 16 + lc];
    tcv[ct] = tcG[ct * 16 + lc];
  }

  const u16* base = agg + (size_t)g * (8 * NN * 8);   // 8 unit-planes x NN x 8 u16
  float fs0 = 0.f, fs1 = 0.f, fs2 = 0.f, fs3 = 0.f;

  for (int rti = 0; rti < 16; ++rti) {
    int arow = (w * 16 + rti) * 16 + lc;
    short8 a0 = *(const short8*)(base + ((size_t)(0 * 4 + lg) * NN + arow) * 8);
    short8 a1 = *(const short8*)(base + ((size_t)(1 * 4 + lg) * NN + arow) * 8);
#define CTILE(CT, FS) { \
    f32x4 acc = {0.f, 0.f, 0.f, 0.f}; \
    acc = __builtin_amdgcn_mfma_f32_16x16x32_bf16(a0, bfr[CT][0], acc, 0, 0, 0); \
    acc = __builtin_amdgcn_mfma_f32_16x16x32_bf16(a1, bfr[CT][1], acc, 0, 0, 0); \
    float s_ = fmaxf(acc[0] * scv[CT] + tcv[CT], 0.f) \
             + fmaxf(acc[1] * scv[CT] + tcv[CT], 0.f) \
             + fmaxf(acc[2] * scv[CT] + tcv[CT], 0.f) \
             + fmaxf(acc[3] * scv[CT] + tcv[CT], 0.f); \
    s_ += __shfl_xor(s_, 16); \
    s_ += __shfl_xor(s_, 32); \
    FS += s_; }
    CTILE(0, fs0) CTILE(1, fs1) CTILE(2, fs2) CTILE(3, fs3)
#undef CTILE
  }
  if (l < 16) {
    part[w][ 0 + l] = fs0;
    part[w][16 + l] = fs1;
    part[w][32 + l] = fs2;
    part[w][48 + l] = fs3;
  }
  __syncthreads();
  if (tid < 64) {
    float s = 0.f;
    #pragma unroll
    for (int q = 0; q < 8; ++q) s += part[q][tid];
    frames[g * 64 + tid] = s * (1.0f / 2048.0f);
  }
}

// =========================================================================
// kC: GRU over T=30 + classifier; one block per batch element
// =========================================================================
__global__ __launch_bounds__(384, 2) void kC(
    const float* __restrict__ frames,
    const float* __restrict__ Wih, const float* __restrict__ Whh,
    const float* __restrict__ bih, const float* __restrict__ bhh,
    const float* __restrict__ Wc1, const float* __restrict__ bc1,
    const float* __restrict__ Wc2, const float* __restrict__ bc2,
    float* __restrict__ out)
{
  const int b = blockIdx.x;
  const int j = threadIdx.x;     // 384 = 3*TEMP gate rows
  __shared__ float xt[64], h[128], GI[384], GH[384], hid[64];
  float wih[64], whh[128];
  const float4* wi4 = (const float4*)(Wih + (size_t)j * 64);
  #pragma unroll
  for (int q = 0; q < 16; ++q) { float4 v = wi4[q]; wih[4*q]=v.x; wih[4*q+1]=v.y; wih[4*q+2]=v.z; wih[4*q+3]=v.w; }
  const float4* wh4 = (const float4*)(Whh + (size_t)j * 128);
  #pragma unroll
  for (int q = 0; q < 32; ++q) { float4 v = wh4[q]; whh[4*q]=v.x; whh[4*q+1]=v.y; whh[4*q+2]=v.z; whh[4*q+3]=v.w; }
  float bi = bih[j], bh = bhh[j];
  if (j < 128) h[j] = 0.f;
  __syncthreads();
  for (int t = 0; t < T_; ++t) {
    if (j < 64) xt[j] = frames[((size_t)b * T_ + t) * 64 + j];
    __syncthreads();
    float gi = bi, gh = bh;
    #pragma unroll
    for (int k = 0; k < 64; ++k) gi += xt[k] * wih[k];
    #pragma unroll
    for (int k = 0; k < 128; ++k) gh += h[k] * whh[k];
    GI[j] = gi; GH[j] = gh;
    __syncthreads();
    if (j < 128) {
      float r = 1.f / (1.f + __expf(-(GI[j] + GH[j])));
      float z = 1.f / (1.f + __expf(-(GI[128 + j] + GH[128 + j])));
      float n = tanhf(GI[256 + j] + r * GH[256 + j]);
      h[j] = (1.f - z) * n + z * h[j];
    }
    __syncthreads();
  }
  if (j < 64) {
    float a = bc1[j];
    #pragma unroll 4
    for (int k = 0; k < 128; ++k) a += h[k] * Wc1[k * 64 + j];
    hid[j] = fmaxf(a, 0.f);
  }
  __syncthreads();
  if (j < 2) {
    float o = bc2[j];
    #pragma unroll
    for (int k = 0; k < 64; ++k) o += hid[k] * Wc2[k * 2 + j];
    out[b * 2 + j] = o;
  }
}

// ---------- launch ----------
extern "C" void kernel_launch(void* const* d_in, const int* in_sizes, int n_in,
                              void* d_out, int out_size, void* d_ws, size_t ws_size,
                              hipStream_t stream) {
  const float* x   = (const float*)d_in[0];
  const int*   ei  = (const int*)d_in[1];
  const float* ew  = (const float*)d_in[2];
  const int*   nid = (const int*)d_in[3];
  const float* W1  = (const float*)d_in[4];
  const float* b1  = (const float*)d_in[5];
  const float* W2  = (const float*)d_in[6];
  const float* b2  = (const float*)d_in[7];
  const float* g1  = (const float*)d_in[8];
  const float* be1 = (const float*)d_in[9];
  const float* m1  = (const float*)d_in[10];
  const float* v1  = (const float*)d_in[11];
  const float* g2  = (const float*)d_in[12];
  const float* be2 = (const float*)d_in[13];
  const float* m2  = (const float*)d_in[14];
  const float* v2  = (const float*)d_in[15];
  const float* Wih = (const float*)d_in[16];
  const float* Whh = (const float*)d_in[17];
  const float* bih = (const float*)d_in[18];
  const float* bhh = (const float*)d_in[19];
  const float* Wc1 = (const float*)d_in[20];
  const float* bc1 = (const float*)d_in[21];
  const float* Wc2 = (const float*)d_in[22];
  const float* bc2 = (const float*)d_in[23];
  float* out = (float*)d_out;

  // workspace layout (bytes), total ~197.2MB (unchanged)
  const size_t REC_OFF   = 0;                    // 62,914,560
  const size_t PL_OFF    = 62914560;             // agg2 8 unit-planes bf16 (+ per-frame stash)
  const size_t META_OFF  = 188743680;            // metaR u32[480*2048]
  const size_t DV2_OFF   = 192675840;            // (unused this round)
  const size_t OFF_OFF   = 196608000;            // u32[480*256]
  const size_t PREP_OFF  = 197099520;            // W2bT 8192 | scG 256 | tcG 256 | W1f 2048 | t1f 256
  const size_t FR_OFF    = 197110528;            // 122,880
  if (ws_size < (size_t)197233408) return;
  (void)DV2_OFF;

  u32*   rec   = (u32*)((char*)d_ws + REC_OFF);
  u16*   agg2  = (u16*)((char*)d_ws + PL_OFF);
  u32*   metaR = (u32*)((char*)d_ws + META_OFF);
  u32*   offG  = (u32*)((char*)d_ws + OFF_OFF);
  u16*   W2bT  = (u16*)((char*)d_ws + PREP_OFF);
  float* scG   = (float*)((char*)d_ws + PREP_OFF + 8192);
  float* tcG   = (float*)((char*)d_ws + PREP_OFF + 8448);
  float* W1f   = (float*)((char*)d_ws + PREP_OFF + 8704);
  float* t1f   = (float*)((char*)d_ws + PREP_OFF + 10752);
  float* frm   = (float*)((char*)d_ws + FR_OFF);

  hipFuncSetAttribute((const void*)kMeta,    hipFuncAttributeMaxDynamicSharedMemorySize, KM_LDS);
  hipFuncSetAttribute((const void*)kScatter, hipFuncAttributeMaxDynamicSharedMemorySize, KS_LDS);
  hipFuncSetAttribute((const void*)kFuse,    hipFuncAttributeMaxDynamicSharedMemorySize, KF_LDS);

  kMeta<<<NF, 1024, KM_LDS, stream>>>(ei, ew, nid, metaR, offG, agg2,
                                      W2, b2, g2, be2, m2, v2,
                                      W1, b1, g1, be1, m1, v1,
                                      W2bT, scG, tcG, W1f, t1f);
  kScatter<<<NF, 1024, KS_LDS, stream>>>(ei, ew, offG, agg2, rec);
  kFuse<<<NF, 1024, KF_LDS, stream>>>(x, rec, metaR, offG, W1f, t1f, agg2);
  kB<<<NF, 512, 0, stream>>>(agg2, W2bT, scG, tcG, frm);
  kC<<<B_, 384, 0, stream>>>(frm, Wih, Whh, bih, bhh, Wc1, bc1, Wc2, bc2, out);
}

// Round 14
// 446.475 us; speedup vs baseline: 1.1233x; 1.0361x over previous
//
#include <hip/hip_runtime.h>
#include <hip/hip_fp16.h>
#include <stdint.h>

#define B_   16
#define T_   30
#define NF   480       // frames = B*T
#define NN   2048      // nodes
#define EE   32768     // edges
#define EPS  1e-5f

typedef unsigned int u32;
typedef unsigned short u16;
typedef __attribute__((ext_vector_type(8))) short short8;   // 8 bf16 = 4 VGPR
typedef __attribute__((ext_vector_type(4))) float f32x4;    // MFMA C/D frag

// ---------- helpers ----------
__device__ __forceinline__ u16 f2bf(float f) {           // RNE f32->bf16
  u32 u = __float_as_uint(f);
  u32 r = u + 0x7FFFu + ((u >> 16) & 1u);
  return (u16)(r >> 16);
}
__device__ __forceinline__ u32 pack2bf(float a, float b) {
  return (u32)f2bf(a) | ((u32)f2bf(b) << 16);
}
__device__ __forceinline__ u16 f2h(float f) { return __half_as_ushort(__float2half(f)); }
__device__ __forceinline__ float h2f(u16 h) { return __half2float(__ushort_as_half(h)); }
__device__ __forceinline__ u32 pack2h(float a, float b) {
  return (u32)f2h(a) | ((u32)f2h(b) << 16);
}

// agg2 frame region (u16 units): 8 planes x NN x 8 = 131072 u16 = 256KB.
// kMeta stashes per-NODE meta at its head (dead until kFuse overwrites):
// nodeP u32[2048] @ u16-off 0..4095, dinvN f16[2048] @ 4096 (kScatter use).
#define AGG_FRAME_U16 131072
#define STASH_DINV_U16 4096

// =========================================================================
// kMeta: sort node_ids -> perm; degrees; rank dsts by length (desc);
//        JDS offsets; exports metaR + dv2R (f32, by rank), nodeP+dinvN
//        (stash for kScatter), offG.  35KB LDS -> 2 blocks/CU.
//        Block 0 also does W-prep.
// =========================================================================
#define KM_KEYS 0        // u32[2048]
#define KM_DEG  8192     // f32[2048]  (degree, then f32 dinv)
#define KM_CNT  16384    // u32[2048]
#define KM_PR   24576    // u32[2048]  perm<<16 | rank
#define KM_HIST 32768    // u32[256]
#define KM_CUM  33792    // u32[256]
#define KM_CUR  34816    // u32[256]
#define KM_LDS  35840

__global__ __launch_bounds__(1024) void kMeta(
    const int* __restrict__ ei, const float* __restrict__ ew, const int* __restrict__ nid,
    u32* __restrict__ metaR, float* __restrict__ dv2R, u32* __restrict__ offG,
    u16* __restrict__ aggStash,
    const float* __restrict__ W2, const float* __restrict__ b2,
    const float* __restrict__ g2, const float* __restrict__ be2,
    const float* __restrict__ m2, const float* __restrict__ v2,
    const float* __restrict__ W1, const float* __restrict__ b1,
    const float* __restrict__ g1, const float* __restrict__ be1,
    const float* __restrict__ m1, const float* __restrict__ v1,
    u16* __restrict__ W2bT, float* __restrict__ scG, float* __restrict__ tcG,
    float* __restrict__ W1f, float* __restrict__ t1f)
{
  extern __shared__ unsigned char smem[];
  const int g = blockIdx.x, t = threadIdx.x;
  const int*   eig  = ei  + (size_t)g * 2 * EE;
  const float* ewg  = ew  + (size_t)g * EE;
  const int*   nidg = nid + (size_t)g * NN;

  u32*  keys = (u32*)(smem + KM_KEYS);
  float* deg = (float*)(smem + KM_DEG);
  u32*  cnt  = (u32*)(smem + KM_CNT);
  u32*  pr   = (u32*)(smem + KM_PR);
  u32*  hist = (u32*)(smem + KM_HIST);
  u32*  cum  = (u32*)(smem + KM_CUM);
  u32*  cur  = (u32*)(smem + KM_CUR);

  u32*  npG  = (u32*)(aggStash + (size_t)g * AGG_FRAME_U16);       // nodeP stash
  u16*  dvG  = aggStash + (size_t)g * AGG_FRAME_U16 + STASH_DINV_U16;

  // keys (stable sort: key = nid<<11 | idx), init
  keys[t]        = ((u32)nidg[t] << 11) | (u32)t;
  keys[t + 1024] = ((u32)nidg[t + 1024] << 11) | (u32)(t + 1024);
  deg[t] = 1.0f; deg[t + 1024] = 1.0f;
  cnt[t] = 0u; cnt[t + 1024] = 0u;
  __syncthreads();

  // bitonic sort, 1 pair/thread/pass
  for (int k = 2; k <= NN; k <<= 1) {
    for (int j = k >> 1; j > 0; j >>= 1) {
      int i = ((t & ~(j - 1)) << 1) | (t & (j - 1));
      int l = i | j;
      u32 x = keys[i], y = keys[l];
      bool up = ((i & k) == 0);
      if ((x > y) == up) { keys[i] = y; keys[l] = x; }
      __syncthreads();
    }
  }
  pr[2*t]   = (keys[2*t]   & 2047u) << 16;   // node i's x-row = perm[i]
  pr[2*t+1] = (keys[2*t+1] & 2047u) << 16;

  // degree (self-loop weight 1) + per-dst edge count
  for (int e = t; e < EE; e += 1024) {
    int d = eig[EE + e];
    atomicAdd(&deg[d], ewg[e]);
    atomicAdd(&cnt[d], 1u);
  }
  __syncthreads();
  {
    float d0 = rsqrtf(deg[2*t]), d1 = rsqrtf(deg[2*t+1]);
    dvG[2*t] = f2h(d0); dvG[2*t+1] = f2h(d1);   // f16 dinv by node (kScatter)
    deg[2*t] = d0; deg[2*t+1] = d1;             // f32 dinv by node (reuse deg)
  }

  // ---- length histogram (256 buckets) ----
  if (t < 256) hist[t] = 0u;
  __syncthreads();
  for (int i = t; i < NN; i += 1024) {
    u32 L = cnt[i];
    atomicAdd(&hist[L < 255u ? L : 255u], 1u);
  }
  __syncthreads();
  if (t < 256) cum[t] = hist[t];
  __syncthreads();
  for (int o = 1; o < 256; o <<= 1) {
    u32 v = 0u;
    if (t < 256 && t >= o) v = cum[t - o];
    __syncthreads();
    if (t < 256) cum[t] += v;
    __syncthreads();
  }
  if (t < 256) cur[t] = (u32)NN - cum[t];   // bucket start (desc order)
  __syncthreads();
  if (t < 256) hist[t] = cur[t];            // scan buffer for off
  __syncthreads();
  for (int o = 1; o < 256; o <<= 1) {
    u32 v = 0u;
    if (t < 256 && t >= o) v = hist[t - o];
    __syncthreads();
    if (t < 256) hist[t] += v;
    __syncthreads();
  }
  if (t < 256) offG[(size_t)g * 256 + t] = hist[t] - cur[t];   // JDS offsets
  __syncthreads();

  // ---- rank assignment (desc length); export metaR + f32 dv2 by rank ----
  for (int i = t; i < NN; i += 1024) {
    u32 L = cnt[i];
    u32 b = L < 255u ? L : 255u;
    u32 r = atomicAdd(&cur[b], 1u);
    pr[i] |= r;
    metaR[(size_t)g * NN + r] = (pr[i] & 0xFFFF0000u) | (L & 0xFFFFu);
    float dv = deg[i];                       // f32 dinv
    dv2R[(size_t)g * NN + r] = dv * dv;
  }
  __syncthreads();
  // export nodeP (perm<<16|rank), coalesced
  npG[2*t]   = pr[2*t];
  npG[2*t+1] = pr[2*t+1];

  // ---- block 0: fold in W-prep ----
  if (g == 0) {
    for (int i = t; i < 4096; i += 1024) {
      int f = i >> 6, k = i & 63;
      W2bT[i] = f2bf(W2[k * 64 + f]);
    }
    if (t < 512) {
      int f = t & 63;
      float sc = g1[f] * rsqrtf(v1[f] + EPS);
      W1f[t] = W1[t] * sc;
    }
    if (t < 64) {
      float sc2 = g2[t] * rsqrtf(v2[t] + EPS);
      scG[t] = sc2;
      tcG[t] = (b2[t] - m2[t]) * sc2 + be2[t];
      float sc1 = g1[t] * rsqrtf(v1[t] + EPS);
      t1f[t] = (b1[t] - m1[t]) * sc1 + be1[t];
    }
  }
}

// =========================================================================
// kScatter: counting-sort edges into JDS rec in LDS; coalesced stream-out.
//   Reads nodeP/dinvN from the agg2-region stash (written by kMeta).
// =========================================================================
#define KS_REC  0        // u32[32768] = 131072
#define KS_CNT  131072   // u32[2048]
#define KS_PR   139264   // u32[2048]
#define KS_DINV 147456   // u16[2048]
#define KS_OFF  151552   // u32[256]
#define KS_LDS  152576

__global__ __launch_bounds__(1024) void kScatter(
    const int* __restrict__ ei, const float* __restrict__ ew,
    const u32* __restrict__ offG, const u16* __restrict__ aggStash,
    u32* __restrict__ recG)
{
  extern __shared__ unsigned char smem[];
  const int g = blockIdx.x, t = threadIdx.x;
  const int*   eig = ei + (size_t)g * 2 * EE;
  const float* ewg = ew + (size_t)g * EE;

  u32* rec   = (u32*)(smem + KS_REC);
  u32* cnt   = (u32*)(smem + KS_CNT);
  u32* prL   = (u32*)(smem + KS_PR);
  u16* dinvL = (u16*)(smem + KS_DINV);
  u32* off   = (u32*)(smem + KS_OFF);

  const u32* npG = (const u32*)(aggStash + (size_t)g * AGG_FRAME_U16);
  const u16* dvG = aggStash + (size_t)g * AGG_FRAME_U16 + STASH_DINV_U16;

  prL[2*t] = npG[2*t]; prL[2*t+1] = npG[2*t+1];
  dinvL[2*t] = dvG[2*t]; dinvL[2*t+1] = dvG[2*t+1];
  cnt[t] = 0u; cnt[t + 1024] = 0u;
  if (t < 256) off[t] = offG[(size_t)g * 256 + t];
  __syncthreads();

  for (int e = t; e < EE; e += 1024) {
    int s = eig[e], d = eig[EE + e];
    float nrm = h2f(dinvL[s]) * ewg[e] * h2f(dinvL[d]);
    u32 k = atomicAdd(&cnt[d], 1u);
    u32 pos = off[k] + (prL[d] & 0xFFFFu);
    rec[pos] = (prL[s] & 0xFFFF0000u) | (u32)f2h(nrm);   // src in ORIG x-row space
  }
  __syncthreads();

  uint4* rg = (uint4*)(recG + (size_t)g * EE);
  const uint4* rl = (const uint4*)rec;
  for (int i = t; i < EE / 4; i += 1024) rg[i] = rl[i];
}

// =========================================================================
// kFuse: thread-per-rank JDS walks; h1 f16[2048][32] in LDS, 2 passes x
//   32 feats; phase C 1-wide + prefetch-1 (one extra live VGPR only).
//   dv2 from f32 dv2R (by rank, coalesced).
// =========================================================================
#define KF_H1   0        // A: xs f32[2048][8] (64KB); B/C: h1 f16[2048][32] (128KB)
#define KF_W1   131072   // f32[512]
#define KF_T1   133120   // f32[64]
#define KF_OFF  133376   // u32[256]
#define KF_LDS  134400

__global__ __launch_bounds__(1024) void kFuse(
    const float* __restrict__ x, const u32* __restrict__ recG,
    const u32* __restrict__ metaR, const float* __restrict__ dv2R,
    const u32* __restrict__ offG,
    const float* __restrict__ W1f, const float* __restrict__ t1f,
    u16* __restrict__ aggOut)
{
  extern __shared__ unsigned char smem[];
  float* xs  = (float*)smem;                  // phase A
  u16*  h1   = (u16*)smem;                    // phases B/C: [2048][32] f16
  float* W1s = (float*)(smem + KF_W1);
  float* t1s = (float*)(smem + KF_T1);
  u32*  offL = (u32*)(smem + KF_OFF);
  const int g = blockIdx.x, t = threadIdx.x;
  const u32* recf = recG + (size_t)g * EE;

  // stage x rows (orig order, coalesced) + constants
  {
    const float4* xg = (const float4*)(x + (size_t)g * NN * 8);
    for (int i = t; i < NN * 2; i += 1024) ((float4*)xs)[i] = xg[i];
  }
  if (t < 512) W1s[t] = W1f[t];
  if (t < 64) t1s[t] = t1f[t];
  if (t >= 512 && t < 768) offL[t - 512] = offG[(size_t)g * 256 + (t - 512)];

  // per-rank meta + f32 dv2 (both rank-major, coalesced)
  u32 origA[2], lenA[2]; float dvA[2];
  #pragma unroll
  for (int it = 0; it < 2; ++it) {
    u32 r = (u32)(it * 1024 + t);
    u32 m = metaR[(size_t)g * NN + r];
    origA[it] = m >> 16; lenA[it] = m & 0xFFFFu;
    dvA[it] = dv2R[(size_t)g * NN + r];
  }
  __syncthreads();

  // ---- phase A: walk-1 in 8-dim x space, agg stays in registers ----
  float agg[2][8];
#define P1(RC) { u32 rc_ = (RC); u32 s_ = rc_ >> 16; \
    float nm_ = h2f((u16)(rc_ & 0xFFFFu)); \
    const float4* xp_ = (const float4*)(smem + (size_t)s_ * 32); \
    float4 a_ = xp_[0], b_ = xp_[1]; \
    ac0 += nm_*a_.x; ac1 += nm_*a_.y; ac2 += nm_*a_.z; ac3 += nm_*a_.w; \
    ac4 += nm_*b_.x; ac5 += nm_*b_.y; ac6 += nm_*b_.z; ac7 += nm_*b_.w; }
  #pragma unroll
  for (int it = 0; it < 2; ++it) {
    u32 r = (u32)(it * 1024 + t);
    float ac0=0,ac1=0,ac2=0,ac3=0,ac4=0,ac5=0,ac6=0,ac7=0;
    int len = (int)lenA[it];
    int j = 0;
    for (; j + 4 <= len; j += 4) {       // JDS: lane-contiguous rec reads
      u32 o0 = offL[j], o1 = offL[j+1], o2 = offL[j+2], o3 = offL[j+3];
      u32 q0 = recf[o0 + r], q1 = recf[o1 + r], q2 = recf[o2 + r], q3 = recf[o3 + r];
      P1(q0) P1(q1) P1(q2) P1(q3)
    }
    for (; j < len; ++j) { P1(recf[offL[j] + r]) }
    {  // self-loop (dv = dinv^2)
      const float4* xd = (const float4*)(smem + (size_t)origA[it] * 32);
      float4 a = xd[0], b = xd[1];
      float dv = dvA[it];
      ac0 += dv*a.x; ac1 += dv*a.y; ac2 += dv*a.z; ac3 += dv*a.w;
      ac4 += dv*b.x; ac5 += dv*b.y; ac6 += dv*b.z; ac7 += dv*b.w;
    }
    agg[it][0]=ac0; agg[it][1]=ac1; agg[it][2]=ac2; agg[it][3]=ac3;
    agg[it][4]=ac4; agg[it][5]=ac5; agg[it][6]=ac6; agg[it][7]=ac7;
  }
#undef P1

  // ---- 2 passes x 32 features ----
  for (int p = 0; p < 2; ++p) {
    __syncthreads();   // pass 0: xs dead; pass 1: previous h1 readers done

    // phase B: h1 slice (feats p*32..p*32+31) from registers, f16, swizzled
    #pragma unroll
    for (int it = 0; it < 2; ++it) {
      float z[32];
      #pragma unroll
      for (int f = 0; f < 32; ++f) z[f] = t1s[p * 32 + f];
      #pragma unroll
      for (int k = 0; k < 8; ++k) {
        float fk = agg[it][k];
        const float4* wr = (const float4*)(W1s + k * 64 + p * 32);
        #pragma unroll
        for (int q = 0; q < 8; ++q) {
          float4 w = wr[q];
          z[4*q]   += fk * w.x; z[4*q+1] += fk * w.y;
          z[4*q+2] += fk * w.z; z[4*q+3] += fk * w.w;
        }
      }
      u32 orig = origA[it];
      u32 sw = (orig >> 1) & 3u;
      uint4* hp = (uint4*)(h1 + (size_t)orig * 32);
      #pragma unroll
      for (int u = 0; u < 4; ++u) {
        int b = u * 8;
        uint4 v = make_uint4(
          pack2h(fmaxf(z[b],   0.f), fmaxf(z[b+1], 0.f)),
          pack2h(fmaxf(z[b+2], 0.f), fmaxf(z[b+3], 0.f)),
          pack2h(fmaxf(z[b+4], 0.f), fmaxf(z[b+5], 0.f)),
          pack2h(fmaxf(z[b+6], 0.f), fmaxf(z[b+7], 0.f)));
        hp[u ^ sw] = v;
      }
    }
    __syncthreads();

    // phase C: walk-2, 32 feats, acc in regs; 1-wide + prefetch-1
#define ROWACC(SRC, NM, OP) { u32 s_ = (SRC); float nm_ = (NM); \
    u32 sw_ = (s_ >> 1) & 3u; \
    const uint4* rp_ = (const uint4*)(h1 + (size_t)s_ * 32); \
    _Pragma("unroll") \
    for (int u = 0; u < 4; ++u) { \
      uint4 w_ = rp_[u ^ sw_]; \
      int b_ = u * 8; \
      acc[b_+0] OP nm_ * h2f((u16)(w_.x & 0xFFFFu)); \
      acc[b_+1] OP nm_ * h2f((u16)(w_.x >> 16)); \
      acc[b_+2] OP nm_ * h2f((u16)(w_.y & 0xFFFFu)); \
      acc[b_+3] OP nm_ * h2f((u16)(w_.y >> 16)); \
      acc[b_+4] OP nm_ * h2f((u16)(w_.z & 0xFFFFu)); \
      acc[b_+5] OP nm_ * h2f((u16)(w_.z >> 16)); \
      acc[b_+6] OP nm_ * h2f((u16)(w_.w & 0xFFFFu)); \
      acc[b_+7] OP nm_ * h2f((u16)(w_.w >> 16)); \
    } }

    for (int it = 0; it < 2; ++it) {
      u32 r = (u32)(it * 1024 + t);
      float acc[32];
      ROWACC(origA[it], dvA[it], =)      // self-loop initializes acc
      int len = (int)lenA[it];
      if (len > 0) {
        u32 qn = recf[offL[0] + r];      // prefetch-1: next record in flight
        int j = 0;
        for (; j < len - 1; ++j) {
          u32 q = qn;
          qn = recf[offL[j + 1] + r];
          ROWACC(q >> 16, h2f((u16)(q & 0xFFFFu)), +=)
        }
        ROWACC(qn >> 16, h2f((u16)(qn & 0xFFFFu)), +=)
      }
      // pass p -> unit-planes p*4..p*4+3 (feats p*32+u*8..+7), 16B/lane
      #pragma unroll
      for (int u = 0; u < 4; ++u) {
        int b = u * 8;
        uint4 o = make_uint4(
          pack2bf(acc[b],   acc[b+1]), pack2bf(acc[b+2], acc[b+3]),
          pack2bf(acc[b+4], acc[b+5]), pack2bf(acc[b+6], acc[b+7]));
        *((uint4*)aggOut + ((size_t)(g * 8 + p * 4 + u)) * NN + r) = o;
      }
    }
#undef ROWACC
  }
}

// =========================================================================
// kB: MFMA GEMM  C = agg2[2048x64](bf16, 8 unit-planes) @ W2(bf16), fused
//     BN+ReLU+mean.  A/B frags share one k-slot bijection.
// =========================================================================
__global__ __launch_bounds__(512) void kB(
    const u16* __restrict__ agg, const u16* __restrict__ W2bT,
    const float* __restrict__ scG, const float* __restrict__ tcG,
    float* __restrict__ frames)
{
  __shared__ u16 W2s[4096];          // bf16 [f=64][k=64]
  __shared__ float part[8][64];
  const int g = blockIdx.x, tid = threadIdx.x;
  const int l = tid & 63, w = tid >> 6;
  const int lc = l & 15, lg = l >> 4;          // frag col / k-group

  ((uint4*)W2s)[tid] = ((const uint4*)W2bT)[tid];
  __syncthreads();

  short8 bfr[4][2];
  float scv[4], tcv[4];
  #pragma unroll
  for (int ct = 0; ct < 4; ++ct) {
    #pragma unroll
    for (int kt = 0; kt < 2; ++kt)
      bfr[ct][kt] = *(const short8*)(W2s + (ct * 16 + lc) * 64 + kt * 32 + lg * 8);
    scv[ct] = scG[ct * 16 + lc];
    tcv[ct] = tcG[ct * 16 + lc];
  }

  const u16* base = agg + (size_t)g * (8 * NN * 8);   // 8 unit-planes x NN x 8 u16
  float fs0 = 0.f, fs1 = 0.f, fs2 = 0.f, fs3 = 0.f;

  for (int rti = 0; rti < 16; ++rti) {
    int arow = (w * 16 + rti) * 16 + lc;
    short8 a0 = *(const short8*)(base + ((size_t)(0 * 4 + lg) * NN + arow) * 8);
    short8 a1 = *(const short8*)(base + ((size_t)(1 * 4 + lg) * NN + arow) * 8);
#define CTILE(CT, FS) { \
    f32x4 acc = {0.f, 0.f, 0.f, 0.f}; \
    acc = __builtin_amdgcn_mfma_f32_16x16x32_bf16(a0, bfr[CT][0], acc, 0, 0, 0); \
    acc = __builtin_amdgcn_mfma_f32_16x16x32_bf16(a1, bfr[CT][1], acc, 0, 0, 0); \
    float s_ = fmaxf(acc[0] * scv[CT] + tcv[CT], 0.f) \
             + fmaxf(acc[1] * scv[CT] + tcv[CT], 0.f) \
             + fmaxf(acc[2] * scv[CT] + tcv[CT], 0.f) \
             + fmaxf(acc[3] * scv[CT] + tcv[CT], 0.f); \
    s_ += __shfl_xor(s_, 16); \
    s_ += __shfl_xor(s_, 32); \
    FS += s_; }
    CTILE(0, fs0) CTILE(1, fs1) CTILE(2, fs2) CTILE(3, fs3)
#undef CTILE
  }
  if (l < 16) {
    part[w][ 0 + l] = fs0;
    part[w][16 + l] = fs1;
    part[w][32 + l] = fs2;
    part[w][48 + l] = fs3;
  }
  __syncthreads();
  if (tid < 64) {
    float s = 0.f;
    #pragma unroll
    for (int q = 0; q < 8; ++q) s += part[q][tid];
    frames[g * 64 + tid] = s * (1.0f / 2048.0f);
  }
}

// =========================================================================
// kC: GRU over T=30 + classifier; one block per batch element
// =========================================================================
__global__ __launch_bounds__(384, 2) void kC(
    const float* __restrict__ frames,
    const float* __restrict__ Wih, const float* __restrict__ Whh,
    const float* __restrict__ bih, const float* __restrict__ bhh,
    const float* __restrict__ Wc1, const float* __restrict__ bc1,
    const float* __restrict__ Wc2, const float* __restrict__ bc2,
    float* __restrict__ out)
{
  const int b = blockIdx.x;
  const int j = threadIdx.x;     // 384 = 3*TEMP gate rows
  __shared__ float xt[64], h[128], GI[384], GH[384], hid[64];
  float wih[64], whh[128];
  const float4* wi4 = (const float4*)(Wih + (size_t)j * 64);
  #pragma unroll
  for (int q = 0; q < 16; ++q) { float4 v = wi4[q]; wih[4*q]=v.x; wih[4*q+1]=v.y; wih[4*q+2]=v.z; wih[4*q+3]=v.w; }
  const float4* wh4 = (const float4*)(Whh + (size_t)j * 128);
  #pragma unroll
  for (int q = 0; q < 32; ++q) { float4 v = wh4[q]; whh[4*q]=v.x; whh[4*q+1]=v.y; whh[4*q+2]=v.z; whh[4*q+3]=v.w; }
  float bi = bih[j], bh = bhh[j];
  if (j < 128) h[j] = 0.f;
  __syncthreads();
  for (int t = 0; t < T_; ++t) {
    if (j < 64) xt[j] = frames[((size_t)b * T_ + t) * 64 + j];
    __syncthreads();
    float gi = bi, gh = bh;
    #pragma unroll
    for (int k = 0; k < 64; ++k) gi += xt[k] * wih[k];
    #pragma unroll
    for (int k = 0; k < 128; ++k) gh += h[k] * whh[k];
    GI[j] = gi; GH[j] = gh;
    __syncthreads();
    if (j < 128) {
      float r = 1.f / (1.f + __expf(-(GI[j] + GH[j])));
      float z = 1.f / (1.f + __expf(-(GI[128 + j] + GH[128 + j])));
      float n = tanhf(GI[256 + j] + r * GH[256 + j]);
      h[j] = (1.f - z) * n + z * h[j];
    }
    __syncthreads();
  }
  if (j < 64) {
    float a = bc1[j];
    #pragma unroll 4
    for (int k = 0; k < 128; ++k) a += h[k] * Wc1[k * 64 + j];
    hid[j] = fmaxf(a, 0.f);
  }
  __syncthreads();
  if (j < 2) {
    float o = bc2[j];
    #pragma unroll
    for (int k = 0; k < 64; ++k) o += hid[k] * Wc2[k * 2 + j];
    out[b * 2 + j] = o;
  }
}

// ---------- launch ----------
extern "C" void kernel_launch(void* const* d_in, const int* in_sizes, int n_in,
                              void* d_out, int out_size, void* d_ws, size_t ws_size,
                              hipStream_t stream) {
  const float* x   = (const float*)d_in[0];
  const int*   ei  = (const int*)d_in[1];
  const float* ew  = (const float*)d_in[2];
  const int*   nid = (const int*)d_in[3];
  const float* W1  = (const float*)d_in[4];
  const float* b1  = (const float*)d_in[5];
  const float* W2  = (const float*)d_in[6];
  const float* b2  = (const float*)d_in[7];
  const float* g1  = (const float*)d_in[8];
  const float* be1 = (const float*)d_in[9];
  const float* m1  = (const float*)d_in[10];
  const float* v1  = (const float*)d_in[11];
  const float* g2  = (const float*)d_in[12];
  const float* be2 = (const float*)d_in[13];
  const float* m2  = (const float*)d_in[14];
  const float* v2  = (const float*)d_in[15];
  const float* Wih = (const float*)d_in[16];
  const float* Whh = (const float*)d_in[17];
  const float* bih = (const float*)d_in[18];
  const float* bhh = (const float*)d_in[19];
  const float* Wc1 = (const float*)d_in[20];
  const float* bc1 = (const float*)d_in[21];
  const float* Wc2 = (const float*)d_in[22];
  const float* bc2 = (const float*)d_in[23];
  float* out = (float*)d_out;

  // workspace layout (bytes), total ~197.2MB (unchanged)
  const size_t REC_OFF   = 0;                    // 62,914,560
  const size_t PL_OFF    = 62914560;             // agg2 8 unit-planes bf16 (+ per-frame stash)
  const size_t META_OFF  = 188743680;            // metaR u32[480*2048]
  const size_t DV2_OFF   = 192675840;            // dv2R f32[480*2048]
  const size_t OFF_OFF   = 196608000;            // u32[480*256]
  const size_t PREP_OFF  = 197099520;            // W2bT 8192 | scG 256 | tcG 256 | W1f 2048 | t1f 256
  const size_t FR_OFF    = 197110528;            // 122,880
  if (ws_size < (size_t)197233408) return;

  u32*   rec   = (u32*)((char*)d_ws + REC_OFF);
  u16*   agg2  = (u16*)((char*)d_ws + PL_OFF);
  u32*   metaR = (u32*)((char*)d_ws + META_OFF);
  float* dv2R  = (float*)((char*)d_ws + DV2_OFF);
  u32*   offG  = (u32*)((char*)d_ws + OFF_OFF);
  u16*   W2bT  = (u16*)((char*)d_ws + PREP_OFF);
  float* scG   = (float*)((char*)d_ws + PREP_OFF + 8192);
  float* tcG   = (float*)((char*)d_ws + PREP_OFF + 8448);
  float* W1f   = (float*)((char*)d_ws + PREP_OFF + 8704);
  float* t1f   = (float*)((char*)d_ws + PREP_OFF + 10752);
  float* frm   = (float*)((char*)d_ws + FR_OFF);

  hipFuncSetAttribute((const void*)kMeta,    hipFuncAttributeMaxDynamicSharedMemorySize, KM_LDS);
  hipFuncSetAttribute((const void*)kScatter, hipFuncAttributeMaxDynamicSharedMemorySize, KS_LDS);
  hipFuncSetAttribute((const void*)kFuse,    hipFuncAttributeMaxDynamicSharedMemorySize, KF_LDS);

  kMeta<<<NF, 1024, KM_LDS, stream>>>(ei, ew, nid, metaR, dv2R, offG, agg2,
                                      W2, b2, g2, be2, m2, v2,
                                      W1, b1, g1, be1, m1, v1,
                                      W2bT, scG, tcG, W1f, t1f);
  kScatter<<<NF, 1024, KS_LDS, stream>>>(ei, ew, offG, agg2, rec);
  kFuse<<<NF, 1024, KF_LDS, stream>>>(x, rec, metaR, dv2R, offG, W1f, t1f, agg2);
  kB<<<NF, 512, 0, stream>>>(agg2, W2bT, scG, tcG, frm);
  kC<<<B_, 384, 0, stream>>>(frm, Wih, Whh, bih, bhh, Wc1, bc1, Wc2, bc2, out);
}

// Round 15
// 425.072 us; speedup vs baseline: 1.1799x; 1.0504x over previous
//
#include <hip/hip_runtime.h>
#include <hip/hip_fp16.h>
#include <stdint.h>

#define B_   16
#define T_   30
#define NF   480       // frames = B*T
#define NN   2048      // nodes
#define EE   32768     // edges
#define EPS  1e-5f

typedef unsigned int u32;
typedef unsigned short u16;
typedef __attribute__((ext_vector_type(8))) short short8;   // 8 bf16 = 4 VGPR
typedef __attribute__((ext_vector_type(4))) float f32x4;    // MFMA C/D frag

// ---------- helpers ----------
__device__ __forceinline__ u16 f2bf(float f) {           // RNE f32->bf16
  u32 u = __float_as_uint(f);
  u32 r = u + 0x7FFFu + ((u >> 16) & 1u);
  return (u16)(r >> 16);
}
__device__ __forceinline__ u32 pack2bf(float a, float b) {
  return (u32)f2bf(a) | ((u32)f2bf(b) << 16);
}
__device__ __forceinline__ u16 f2h(float f) { return __half_as_ushort(__float2half(f)); }
__device__ __forceinline__ float h2f(u16 h) { return __half2float(__ushort_as_half(h)); }
__device__ __forceinline__ u32 pack2h(float a, float b) {
  return (u32)f2h(a) | ((u32)f2h(b) << 16);
}

// agg2 frame region (u16 units): 8 planes x NN x 8 = 131072 u16 = 256KB.
// kMeta stashes per-NODE meta at its head (dead until kFuse overwrites):
// nodeP u32[2048] @ u16-off 0..4095, dinvN f16[2048] @ 4096 (kScatter use).
#define AGG_FRAME_U16 131072
#define STASH_DINV_U16 4096

// =========================================================================
// kMeta: sort node_ids -> perm; degrees; rank dsts by length (desc);
//        JDS offsets; exports metaR + dv2R (f32, by rank), nodeP+dinvN
//        (stash for kScatter), offG.  35KB LDS -> 2 blocks/CU.
//        Block 0 also does W-prep.
// =========================================================================
#define KM_KEYS 0        // u32[2048]
#define KM_DEG  8192     // f32[2048]  (degree, then f32 dinv)
#define KM_CNT  16384    // u32[2048]
#define KM_PR   24576    // u32[2048]  perm<<16 | rank
#define KM_HIST 32768    // u32[256]
#define KM_CUM  33792    // u32[256]
#define KM_CUR  34816    // u32[256]
#define KM_LDS  35840

__global__ __launch_bounds__(1024) void kMeta(
    const int* __restrict__ ei, const float* __restrict__ ew, const int* __restrict__ nid,
    u32* __restrict__ metaR, float* __restrict__ dv2R, u32* __restrict__ offG,
    u16* __restrict__ aggStash,
    const float* __restrict__ W2, const float* __restrict__ b2,
    const float* __restrict__ g2, const float* __restrict__ be2,
    const float* __restrict__ m2, const float* __restrict__ v2,
    const float* __restrict__ W1, const float* __restrict__ b1,
    const float* __restrict__ g1, const float* __restrict__ be1,
    const float* __restrict__ m1, const float* __restrict__ v1,
    u16* __restrict__ W2bT, float* __restrict__ scG, float* __restrict__ tcG,
    float* __restrict__ W1f, float* __restrict__ t1f)
{
  extern __shared__ unsigned char smem[];
  const int g = blockIdx.x, t = threadIdx.x;
  const int*   eig  = ei  + (size_t)g * 2 * EE;
  const float* ewg  = ew  + (size_t)g * EE;
  const int*   nidg = nid + (size_t)g * NN;

  u32*  keys = (u32*)(smem + KM_KEYS);
  float* deg = (float*)(smem + KM_DEG);
  u32*  cnt  = (u32*)(smem + KM_CNT);
  u32*  pr   = (u32*)(smem + KM_PR);
  u32*  hist = (u32*)(smem + KM_HIST);
  u32*  cum  = (u32*)(smem + KM_CUM);
  u32*  cur  = (u32*)(smem + KM_CUR);

  u32*  npG  = (u32*)(aggStash + (size_t)g * AGG_FRAME_U16);       // nodeP stash
  u16*  dvG  = aggStash + (size_t)g * AGG_FRAME_U16 + STASH_DINV_U16;

  // keys (stable sort: key = nid<<11 | idx), init
  keys[t]        = ((u32)nidg[t] << 11) | (u32)t;
  keys[t + 1024] = ((u32)nidg[t + 1024] << 11) | (u32)(t + 1024);
  deg[t] = 1.0f; deg[t + 1024] = 1.0f;
  cnt[t] = 0u; cnt[t + 1024] = 0u;
  __syncthreads();

  // bitonic sort, 1 pair/thread/pass
  for (int k = 2; k <= NN; k <<= 1) {
    for (int j = k >> 1; j > 0; j >>= 1) {
      int i = ((t & ~(j - 1)) << 1) | (t & (j - 1));
      int l = i | j;
      u32 x = keys[i], y = keys[l];
      bool up = ((i & k) == 0);
      if ((x > y) == up) { keys[i] = y; keys[l] = x; }
      __syncthreads();
    }
  }
  pr[2*t]   = (keys[2*t]   & 2047u) << 16;   // node i's x-row = perm[i]
  pr[2*t+1] = (keys[2*t+1] & 2047u) << 16;

  // degree (self-loop weight 1) + per-dst edge count
  for (int e = t; e < EE; e += 1024) {
    int d = eig[EE + e];
    atomicAdd(&deg[d], ewg[e]);
    atomicAdd(&cnt[d], 1u);
  }
  __syncthreads();
  {
    float d0 = rsqrtf(deg[2*t]), d1 = rsqrtf(deg[2*t+1]);
    dvG[2*t] = f2h(d0); dvG[2*t+1] = f2h(d1);   // f16 dinv by node (kScatter)
    deg[2*t] = d0; deg[2*t+1] = d1;             // f32 dinv by node (reuse deg)
  }

  // ---- length histogram (256 buckets) ----
  if (t < 256) hist[t] = 0u;
  __syncthreads();
  for (int i = t; i < NN; i += 1024) {
    u32 L = cnt[i];
    atomicAdd(&hist[L < 255u ? L : 255u], 1u);
  }
  __syncthreads();
  if (t < 256) cum[t] = hist[t];
  __syncthreads();
  for (int o = 1; o < 256; o <<= 1) {
    u32 v = 0u;
    if (t < 256 && t >= o) v = cum[t - o];
    __syncthreads();
    if (t < 256) cum[t] += v;
    __syncthreads();
  }
  if (t < 256) cur[t] = (u32)NN - cum[t];   // bucket start (desc order)
  __syncthreads();
  if (t < 256) hist[t] = cur[t];            // scan buffer for off
  __syncthreads();
  for (int o = 1; o < 256; o <<= 1) {
    u32 v = 0u;
    if (t < 256 && t >= o) v = hist[t - o];
    __syncthreads();
    if (t < 256) hist[t] += v;
    __syncthreads();
  }
  if (t < 256) offG[(size_t)g * 256 + t] = hist[t] - cur[t];   // JDS offsets
  __syncthreads();

  // ---- rank assignment (desc length); export metaR + f32 dv2 by rank ----
  for (int i = t; i < NN; i += 1024) {
    u32 L = cnt[i];
    u32 b = L < 255u ? L : 255u;
    u32 r = atomicAdd(&cur[b], 1u);
    pr[i] |= r;
    metaR[(size_t)g * NN + r] = (pr[i] & 0xFFFF0000u) | (L & 0xFFFFu);
    float dv = deg[i];                       // f32 dinv
    dv2R[(size_t)g * NN + r] = dv * dv;
  }
  __syncthreads();
  // export nodeP (perm<<16|rank), coalesced
  npG[2*t]   = pr[2*t];
  npG[2*t+1] = pr[2*t+1];

  // ---- block 0: fold in W-prep ----
  if (g == 0) {
    for (int i = t; i < 4096; i += 1024) {
      int f = i >> 6, k = i & 63;
      W2bT[i] = f2bf(W2[k * 64 + f]);
    }
    if (t < 512) {
      int f = t & 63;
      float sc = g1[f] * rsqrtf(v1[f] + EPS);
      W1f[t] = W1[t] * sc;
    }
    if (t < 64) {
      float sc2 = g2[t] * rsqrtf(v2[t] + EPS);
      scG[t] = sc2;
      tcG[t] = (b2[t] - m2[t]) * sc2 + be2[t];
      float sc1 = g1[t] * rsqrtf(v1[t] + EPS);
      t1f[t] = (b1[t] - m1[t]) * sc1 + be1[t];
    }
  }
}

// =========================================================================
// kScatter: counting-sort edges into JDS rec in LDS; coalesced stream-out.
//   Reads nodeP/dinvN from the agg2-region stash (written by kMeta).
// =========================================================================
#define KS_REC  0        // u32[32768] = 131072
#define KS_CNT  131072   // u32[2048]
#define KS_PR   139264   // u32[2048]
#define KS_DINV 147456   // u16[2048]
#define KS_OFF  151552   // u32[256]
#define KS_LDS  152576

__global__ __launch_bounds__(1024) void kScatter(
    const int* __restrict__ ei, const float* __restrict__ ew,
    const u32* __restrict__ offG, const u16* __restrict__ aggStash,
    u32* __restrict__ recG)
{
  extern __shared__ unsigned char smem[];
  const int g = blockIdx.x, t = threadIdx.x;
  const int*   eig = ei + (size_t)g * 2 * EE;
  const float* ewg = ew + (size_t)g * EE;

  u32* rec   = (u32*)(smem + KS_REC);
  u32* cnt   = (u32*)(smem + KS_CNT);
  u32* prL   = (u32*)(smem + KS_PR);
  u16* dinvL = (u16*)(smem + KS_DINV);
  u32* off   = (u32*)(smem + KS_OFF);

  const u32* npG = (const u32*)(aggStash + (size_t)g * AGG_FRAME_U16);
  const u16* dvG = aggStash + (size_t)g * AGG_FRAME_U16 + STASH_DINV_U16;

  prL[2*t] = npG[2*t]; prL[2*t+1] = npG[2*t+1];
  dinvL[2*t] = dvG[2*t]; dinvL[2*t+1] = dvG[2*t+1];
  cnt[t] = 0u; cnt[t + 1024] = 0u;
  if (t < 256) off[t] = offG[(size_t)g * 256 + t];
  __syncthreads();

  for (int e = t; e < EE; e += 1024) {
    int s = eig[e], d = eig[EE + e];
    float nrm = h2f(dinvL[s]) * ewg[e] * h2f(dinvL[d]);
    u32 k = atomicAdd(&cnt[d], 1u);
    u32 pos = off[k] + (prL[d] & 0xFFFFu);
    rec[pos] = (prL[s] & 0xFFFF0000u) | (u32)f2h(nrm);   // src in ORIG x-row space
  }
  __syncthreads();

  uint4* rg = (uint4*)(recG + (size_t)g * EE);
  const uint4* rl = (const uint4*)rec;
  for (int i = t; i < EE / 4; i += 1024) rg[i] = rl[i];
}

// =========================================================================
// kFuse v9: thread-per-rank JDS walks; h1 f16[2048][16] in LDS (64KB,
//   shared with phase-A xs f32[2048][8]); 4 passes x 16 feats.
//   LDS 67.25KB -> 2 blocks/CU = 32 waves (2x TLP vs r14's 16).
//   Phase C 1-wide + prefetch-1.  dv2 from f32 dv2R.
// =========================================================================
#define KF_H1   0        // A: xs f32[2048][8] (64KB); B/C: h1 f16[2048][16] (64KB)
#define KF_W1   65536    // f32[512]
#define KF_T1   67584    // f32[64]
#define KF_OFF  67840    // u32[256]
#define KF_LDS  68864

__global__ __launch_bounds__(1024) void kFuse(
    const float* __restrict__ x, const u32* __restrict__ recG,
    const u32* __restrict__ metaR, const float* __restrict__ dv2R,
    const u32* __restrict__ offG,
    const float* __restrict__ W1f, const float* __restrict__ t1f,
    u16* __restrict__ aggOut)
{
  extern __shared__ unsigned char smem[];
  u16*  h1   = (u16*)smem;                    // phases B/C: [2048][16] f16, 32B rows
  float* W1s = (float*)(smem + KF_W1);
  float* t1s = (float*)(smem + KF_T1);
  u32*  offL = (u32*)(smem + KF_OFF);
  const int g = blockIdx.x, t = threadIdx.x;
  const u32* recf = recG + (size_t)g * EE;

  // stage x rows (orig order, coalesced) + constants
  {
    const float4* xg = (const float4*)(x + (size_t)g * NN * 8);
    for (int i = t; i < NN * 2; i += 1024) ((float4*)smem)[i] = xg[i];
  }
  if (t < 512) W1s[t] = W1f[t];
  if (t < 64) t1s[t] = t1f[t];
  if (t >= 512 && t < 768) offL[t - 512] = offG[(size_t)g * 256 + (t - 512)];

  // per-rank meta + f32 dv2 (both rank-major, coalesced)
  u32 origA[2], lenA[2]; float dvA[2];
  #pragma unroll
  for (int it = 0; it < 2; ++it) {
    u32 r = (u32)(it * 1024 + t);
    u32 m = metaR[(size_t)g * NN + r];
    origA[it] = m >> 16; lenA[it] = m & 0xFFFFu;
    dvA[it] = dv2R[(size_t)g * NN + r];
  }
  __syncthreads();

  // ---- phase A: walk-1 in 8-dim x space, agg stays in registers ----
  float agg[2][8];
#define P1(RC) { u32 rc_ = (RC); u32 s_ = rc_ >> 16; \
    float nm_ = h2f((u16)(rc_ & 0xFFFFu)); \
    const float4* xp_ = (const float4*)(smem + (size_t)s_ * 32); \
    float4 a_ = xp_[0], b_ = xp_[1]; \
    ac0 += nm_*a_.x; ac1 += nm_*a_.y; ac2 += nm_*a_.z; ac3 += nm_*a_.w; \
    ac4 += nm_*b_.x; ac5 += nm_*b_.y; ac6 += nm_*b_.z; ac7 += nm_*b_.w; }
  #pragma unroll
  for (int it = 0; it < 2; ++it) {
    u32 r = (u32)(it * 1024 + t);
    float ac0=0,ac1=0,ac2=0,ac3=0,ac4=0,ac5=0,ac6=0,ac7=0;
    int len = (int)lenA[it];
    int j = 0;
    for (; j + 4 <= len; j += 4) {       // JDS: lane-contiguous rec reads
      u32 o0 = offL[j], o1 = offL[j+1], o2 = offL[j+2], o3 = offL[j+3];
      u32 q0 = recf[o0 + r], q1 = recf[o1 + r], q2 = recf[o2 + r], q3 = recf[o3 + r];
      P1(q0) P1(q1) P1(q2) P1(q3)
    }
    for (; j < len; ++j) { P1(recf[offL[j] + r]) }
    {  // self-loop (dv = dinv^2)
      const float4* xd = (const float4*)(smem + (size_t)origA[it] * 32);
      float4 a = xd[0], b = xd[1];
      float dv = dvA[it];
      ac0 += dv*a.x; ac1 += dv*a.y; ac2 += dv*a.z; ac3 += dv*a.w;
      ac4 += dv*b.x; ac5 += dv*b.y; ac6 += dv*b.z; ac7 += dv*b.w;
    }
    agg[it][0]=ac0; agg[it][1]=ac1; agg[it][2]=ac2; agg[it][3]=ac3;
    agg[it][4]=ac4; agg[it][5]=ac5; agg[it][6]=ac6; agg[it][7]=ac7;
  }
#undef P1

  // ---- 4 passes x 16 features ----
  for (int p = 0; p < 4; ++p) {
    __syncthreads();   // pass 0: xs dead; later: previous h1 readers done

    // phase B: h1 slice (feats p*16..p*16+15) from registers, f16, swizzled
    #pragma unroll
    for (int it = 0; it < 2; ++it) {
      float z[16];
      #pragma unroll
      for (int f = 0; f < 16; ++f) z[f] = t1s[p * 16 + f];
      #pragma unroll
      for (int k = 0; k < 8; ++k) {
        float fk = agg[it][k];
        const float4* wr = (const float4*)(W1s + k * 64 + p * 16);
        #pragma unroll
        for (int q = 0; q < 4; ++q) {
          float4 w = wr[q];
          z[4*q]   += fk * w.x; z[4*q+1] += fk * w.y;
          z[4*q+2] += fk * w.z; z[4*q+3] += fk * w.w;
        }
      }
      u32 orig = origA[it];
      u32 sw = (orig >> 2) & 1u;
      uint4* hp = (uint4*)(h1 + (size_t)orig * 16);
      #pragma unroll
      for (int u = 0; u < 2; ++u) {
        int b = u * 8;
        uint4 v = make_uint4(
          pack2h(fmaxf(z[b],   0.f), fmaxf(z[b+1], 0.f)),
          pack2h(fmaxf(z[b+2], 0.f), fmaxf(z[b+3], 0.f)),
          pack2h(fmaxf(z[b+4], 0.f), fmaxf(z[b+5], 0.f)),
          pack2h(fmaxf(z[b+6], 0.f), fmaxf(z[b+7], 0.f)));
        hp[u ^ sw] = v;
      }
    }
    __syncthreads();

    // phase C: walk-2, 16 feats, acc in regs; 1-wide + prefetch-1
#define ROWACC(SRC, NM, OP) { u32 s_ = (SRC); float nm_ = (NM); \
    u32 sw_ = (s_ >> 2) & 1u; \
    const uint4* rp_ = (const uint4*)(h1 + (size_t)s_ * 16); \
    _Pragma("unroll") \
    for (int u = 0; u < 2; ++u) { \
      uint4 w_ = rp_[u ^ sw_]; \
      int b_ = u * 8; \
      acc[b_+0] OP nm_ * h2f((u16)(w_.x & 0xFFFFu)); \
      acc[b_+1] OP nm_ * h2f((u16)(w_.x >> 16)); \
      acc[b_+2] OP nm_ * h2f((u16)(w_.y & 0xFFFFu)); \
      acc[b_+3] OP nm_ * h2f((u16)(w_.y >> 16)); \
      acc[b_+4] OP nm_ * h2f((u16)(w_.z & 0xFFFFu)); \
      acc[b_+5] OP nm_ * h2f((u16)(w_.z >> 16)); \
      acc[b_+6] OP nm_ * h2f((u16)(w_.w & 0xFFFFu)); \
      acc[b_+7] OP nm_ * h2f((u16)(w_.w >> 16)); \
    } }

    for (int it = 0; it < 2; ++it) {
      u32 r = (u32)(it * 1024 + t);
      float acc[16];
      ROWACC(origA[it], dvA[it], =)      // self-loop initializes acc
      int len = (int)lenA[it];
      if (len > 0) {
        u32 qn = recf[offL[0] + r];      // prefetch-1
        int j = 0;
        for (; j < len - 1; ++j) {
          u32 q = qn;
          qn = recf[offL[j + 1] + r];
          ROWACC(q >> 16, h2f((u16)(q & 0xFFFFu)), +=)
        }
        ROWACC(qn >> 16, h2f((u16)(qn & 0xFFFFu)), +=)
      }
      // pass p -> unit-planes p*2, p*2+1 (feats p*16+u*8..+7), 16B/lane
      #pragma unroll
      for (int u = 0; u < 2; ++u) {
        int b = u * 8;
        uint4 o = make_uint4(
          pack2bf(acc[b],   acc[b+1]), pack2bf(acc[b+2], acc[b+3]),
          pack2bf(acc[b+4], acc[b+5]), pack2bf(acc[b+6], acc[b+7]));
        *((uint4*)aggOut + ((size_t)(g * 8 + p * 2 + u)) * NN + r) = o;
      }
    }
#undef ROWACC
  }
}

// =========================================================================
// kB: MFMA GEMM  C = agg2[2048x64](bf16, 8 unit-planes) @ W2(bf16), fused
//     BN+ReLU+mean.  A/B frags share one k-slot bijection.
// =========================================================================
__global__ __launch_bounds__(512) void kB(
    const u16* __restrict__ agg, const u16* __restrict__ W2bT,
    const float* __restrict__ scG, const float* __restrict__ tcG,
    float* __restrict__ frames)
{
  __shared__ u16 W2s[4096];          // bf16 [f=64][k=64]
  __shared__ float part[8][64];
  const int g = blockIdx.x, tid = threadIdx.x;
  const int l = tid & 63, w = tid >> 6;
  const int lc = l & 15, lg = l >> 4;          // frag col / k-group

  ((uint4*)W2s)[tid] = ((const uint4*)W2bT)[tid];
  __syncthreads();

  short8 bfr[4][2];
  float scv[4], tcv[4];
  #pragma unroll
  for (int ct = 0; ct < 4; ++ct) {
    #pragma unroll
    for (int kt = 0; kt < 2; ++kt)
      bfr[ct][kt] = *(const short8*)(W2s + (ct * 16 + lc) * 64 + kt * 32 + lg * 8);
    scv[ct] = scG[ct * 16 + lc];
    tcv[ct] = tcG[ct * 16 + lc];
  }

  const u16* base = agg + (size_t)g * (8 * NN * 8);   // 8 unit-planes x NN x 8 u16
  float fs0 = 0.f, fs1 = 0.f, fs2 = 0.f, fs3 = 0.f;

  for (int rti = 0; rti < 16; ++rti) {
    int arow = (w * 16 + rti) * 16 + lc;
    short8 a0 = *(const short8*)(base + ((size_t)(0 * 4 + lg) * NN + arow) * 8);
    short8 a1 = *(const short8*)(base + ((size_t)(1 * 4 + lg) * NN + arow) * 8);
#define CTILE(CT, FS) { \
    f32x4 acc = {0.f, 0.f, 0.f, 0.f}; \
    acc = __builtin_amdgcn_mfma_f32_16x16x32_bf16(a0, bfr[CT][0], acc, 0, 0, 0); \
    acc = __builtin_amdgcn_mfma_f32_16x16x32_bf16(a1, bfr[CT][1], acc, 0, 0, 0); \
    float s_ = fmaxf(acc[0] * scv[CT] + tcv[CT], 0.f) \
             + fmaxf(acc[1] * scv[CT] + tcv[CT], 0.f) \
             + fmaxf(acc[2] * scv[CT] + tcv[CT], 0.f) \
             + fmaxf(acc[3] * scv[CT] + tcv[CT], 0.f); \
    s_ += __shfl_xor(s_, 16); \
    s_ += __shfl_xor(s_, 32); \
    FS += s_; }
    CTILE(0, fs0) CTILE(1, fs1) CTILE(2, fs2) CTILE(3, fs3)
#undef CTILE
  }
  if (l < 16) {
    part[w][ 0 + l] = fs0;
    part[w][16 + l] = fs1;
    part[w][32 + l] = fs2;
    part[w][48 + l] = fs3;
  }
  __syncthreads();
  if (tid < 64) {
    float s = 0.f;
    #pragma unroll
    for (int q = 0; q < 8; ++q) s += part[q][tid];
    frames[g * 64 + tid] = s * (1.0f / 2048.0f);
  }
}

// =========================================================================
// kC: GRU over T=30 + classifier; one block per batch element
// =========================================================================
__global__ __launch_bounds__(384, 2) void kC(
    const float* __restrict__ frames,
    const float* __restrict__ Wih, const float* __restrict__ Whh,
    const float* __restrict__ bih, const float* __restrict__ bhh,
    const float* __restrict__ Wc1, const float* __restrict__ bc1,
    const float* __restrict__ Wc2, const float* __restrict__ bc2,
    float* __restrict__ out)
{
  const int b = blockIdx.x;
  const int j = threadIdx.x;     // 384 = 3*TEMP gate rows
  __shared__ float xt[64], h[128], GI[384], GH[384], hid[64];
  float wih[64], whh[128];
  const float4* wi4 = (const float4*)(Wih + (size_t)j * 64);
  #pragma unroll
  for (int q = 0; q < 16; ++q) { float4 v = wi4[q]; wih[4*q]=v.x; wih[4*q+1]=v.y; wih[4*q+2]=v.z; wih[4*q+3]=v.w; }
  const float4* wh4 = (const float4*)(Whh + (size_t)j * 128);
  #pragma unroll
  for (int q = 0; q < 32; ++q) { float4 v = wh4[q]; whh[4*q]=v.x; whh[4*q+1]=v.y; whh[4*q+2]=v.z; whh[4*q+3]=v.w; }
  float bi = bih[j], bh = bhh[j];
  if (j < 128) h[j] = 0.f;
  __syncthreads();
  for (int t = 0; t < T_; ++t) {
    if (j < 64) xt[j] = frames[((size_t)b * T_ + t) * 64 + j];
    __syncthreads();
    float gi = bi, gh = bh;
    #pragma unroll
    for (int k = 0; k < 64; ++k) gi += xt[k] * wih[k];
    #pragma unroll
    for (int k = 0; k < 128; ++k) gh += h[k] * whh[k];
    GI[j] = gi; GH[j] = gh;
    __syncthreads();
    if (j < 128) {
      float r = 1.f / (1.f + __expf(-(GI[j] + GH[j])));
      float z = 1.f / (1.f + __expf(-(GI[128 + j] + GH[128 + j])));
      float n = tanhf(GI[256 + j] + r * GH[256 + j]);
      h[j] = (1.f - z) * n + z * h[j];
    }
    __syncthreads();
  }
  if (j < 64) {
    float a = bc1[j];
    #pragma unroll 4
    for (int k = 0; k < 128; ++k) a += h[k] * Wc1[k * 64 + j];
    hid[j] = fmaxf(a, 0.f);
  }
  __syncthreads();
  if (j < 2) {
    float o = bc2[j];
    #pragma unroll
    for (int k = 0; k < 64; ++k) o += hid[k] * Wc2[k * 2 + j];
    out[b * 2 + j] = o;
  }
}

// ---------- launch ----------
extern "C" void kernel_launch(void* const* d_in, const int* in_sizes, int n_in,
                              void* d_out, int out_size, void* d_ws, size_t ws_size,
                              hipStream_t stream) {
  const float* x   = (const float*)d_in[0];
  const int*   ei  = (const int*)d_in[1];
  const float* ew  = (const float*)d_in[2];
  const int*   nid = (const int*)d_in[3];
  const float* W1  = (const float*)d_in[4];
  const float* b1  = (const float*)d_in[5];
  const float* W2  = (const float*)d_in[6];
  const float* b2  = (const float*)d_in[7];
  const float* g1  = (const float*)d_in[8];
  const float* be1 = (const float*)d_in[9];
  const float* m1  = (const float*)d_in[10];
  const float* v1  = (const float*)d_in[11];
  const float* g2  = (const float*)d_in[12];
  const float* be2 = (const float*)d_in[13];
  const float* m2  = (const float*)d_in[14];
  const float* v2  = (const float*)d_in[15];
  const float* Wih = (const float*)d_in[16];
  const float* Whh = (const float*)d_in[17];
  const float* bih = (const float*)d_in[18];
  const float* bhh = (const float*)d_in[19];
  const float* Wc1 = (const float*)d_in[20];
  const float* bc1 = (const float*)d_in[21];
  const float* Wc2 = (const float*)d_in[22];
  const float* bc2 = (const float*)d_in[23];
  float* out = (float*)d_out;

  // workspace layout (bytes), total ~197.2MB (unchanged)
  const size_t REC_OFF   = 0;                    // 62,914,560
  const size_t PL_OFF    = 62914560;             // agg2 8 unit-planes bf16 (+ per-frame stash)
  const size_t META_OFF  = 188743680;            // metaR u32[480*2048]
  const size_t DV2_OFF   = 192675840;            // dv2R f32[480*2048]
  const size_t OFF_OFF   = 196608000;            // u32[480*256]
  const size_t PREP_OFF  = 197099520;            // W2bT 8192 | scG 256 | tcG 256 | W1f 2048 | t1f 256
  const size_t FR_OFF    = 197110528;            // 122,880
  if (ws_size < (size_t)197233408) return;

  u32*   rec   = (u32*)((char*)d_ws + REC_OFF);
  u16*   agg2  = (u16*)((char*)d_ws + PL_OFF);
  u32*   metaR = (u32*)((char*)d_ws + META_OFF);
  float* dv2R  = (float*)((char*)d_ws + DV2_OFF);
  u32*   offG  = (u32*)((char*)d_ws + OFF_OFF);
  u16*   W2bT  = (u16*)((char*)d_ws + PREP_OFF);
  float* scG   = (float*)((char*)d_ws + PREP_OFF + 8192);
  float* tcG   = (float*)((char*)d_ws + PREP_OFF + 8448);
  float* W1f   = (float*)((char*)d_ws + PREP_OFF + 8704);
  float* t1f   = (float*)((char*)d_ws + PREP_OFF + 10752);
  float* frm   = (float*)((char*)d_ws + FR_OFF);

  hipFuncSetAttribute((const void*)kMeta,    hipFuncAttributeMaxDynamicSharedMemorySize, KM_LDS);
  hipFuncSetAttribute((const void*)kScatter, hipFuncAttributeMaxDynamicSharedMemorySize, KS_LDS);
  hipFuncSetAttribute((const void*)kFuse,    hipFuncAttributeMaxDynamicSharedMemorySize, KF_LDS);

  kMeta<<<NF, 1024, KM_LDS, stream>>>(ei, ew, nid, metaR, dv2R, offG, agg2,
                                      W2, b2, g2, be2, m2, v2,
                                      W1, b1, g1, be1, m1, v1,
                                      W2bT, scG, tcG, W1f, t1f);
  kScatter<<<NF, 1024, KS_LDS, stream>>>(ei, ew, offG, agg2, rec);
  kFuse<<<NF, 1024, KF_LDS, stream>>>(x, rec, metaR, dv2R, offG, W1f, t1f, agg2);
  kB<<<NF, 512, 0, stream>>>(agg2, W2bT, scG, tcG, frm);
  kC<<<B_, 384, 0, stream>>>(frm, Wih, Whh, bih, bhh, Wc1, bc1, Wc2, bc2, out);
}

// Round 16
// 419.555 us; speedup vs baseline: 1.1954x; 1.0132x over previous
//
#include <hip/hip_runtime.h>
#include <hip/hip_fp16.h>
#include <stdint.h>

#define B_   16
#define T_   30
#define NF   480       // frames = B*T
#define NN   2048      // nodes
#define EE   32768     // edges
#define EPS  1e-5f

typedef unsigned int u32;
typedef unsigned short u16;
typedef __attribute__((ext_vector_type(8))) short short8;   // 8 bf16 = 4 VGPR
typedef __attribute__((ext_vector_type(4))) float f32x4;    // MFMA C/D frag

// ---------- helpers ----------
__device__ __forceinline__ u16 f2bf(float f) {           // RNE f32->bf16
  u32 u = __float_as_uint(f);
  u32 r = u + 0x7FFFu + ((u >> 16) & 1u);
  return (u16)(r >> 16);
}
__device__ __forceinline__ u32 pack2bf(float a, float b) {
  return (u32)f2bf(a) | ((u32)f2bf(b) << 16);
}
__device__ __forceinline__ u16 f2h(float f) { return __half_as_ushort(__float2half(f)); }
__device__ __forceinline__ float h2f(u16 h) { return __half2float(__ushort_as_half(h)); }
__device__ __forceinline__ u32 pack2h(float a, float b) {
  return (u32)f2h(a) | ((u32)f2h(b) << 16);
}

// agg2 frame region (u16 units): 8 planes x NN x 8 = 131072 u16 = 256KB.
// kMeta stashes per-NODE meta at its head (dead until kFuse overwrites):
// nodeP u32[2048] @ u16-off 0..4095, dinvN f16[2048] @ 4096 (kScatter use).
#define AGG_FRAME_U16 131072
#define STASH_DINV_U16 4096

// =========================================================================
// kMeta v2: bucket-sort replaces bitonic (unique 31-bit keys).
//   sort: hist(2048 bins on key>>20) -> scan -> atomic scatter -> exact
//   in-bucket rank (avg ~2 compares) -> sorted keys.  ~8 barriers vs 66.
//   Then degrees, length-ranking, JDS offsets, exports (as before).
//   44KB LDS -> 3 blocks/CU.  Block 0 also does W-prep.
// =========================================================================
#define KM_A    0        // u32[2048]  keys (final sorted)
#define KM_B    8192     // u32[2048]  scan aux / scattered tmp
#define KM_C    16384    // u32[2048]  bucket starts ; later deg f32
#define KM_D    24576    // u32[2048]  bucket cnt/cursor ; later cnt
#define KM_PR   32768    // u32[2048]  perm<<16 | rank
#define KM_HIST 40960    // u32[256]
#define KM_CUM  41984    // u32[256]
#define KM_CUR  43008    // u32[256]
#define KM_LDS  44032

__global__ __launch_bounds__(1024) void kMeta(
    const int* __restrict__ ei, const float* __restrict__ ew, const int* __restrict__ nid,
    u32* __restrict__ metaR, float* __restrict__ dv2R, u32* __restrict__ offG,
    u16* __restrict__ aggStash,
    const float* __restrict__ W2, const float* __restrict__ b2,
    const float* __restrict__ g2, const float* __restrict__ be2,
    const float* __restrict__ m2, const float* __restrict__ v2,
    const float* __restrict__ W1, const float* __restrict__ b1,
    const float* __restrict__ g1, const float* __restrict__ be1,
    const float* __restrict__ m1, const float* __restrict__ v1,
    u16* __restrict__ W2bT, float* __restrict__ scG, float* __restrict__ tcG,
    float* __restrict__ W1f, float* __restrict__ t1f)
{
  extern __shared__ unsigned char smem[];
  const int g = blockIdx.x, t = threadIdx.x;
  const int*   eig  = ei  + (size_t)g * 2 * EE;
  const float* ewg  = ew  + (size_t)g * EE;
  const int*   nidg = nid + (size_t)g * NN;

  u32*  A    = (u32*)(smem + KM_A);
  u32*  Btmp = (u32*)(smem + KM_B);
  u32*  C    = (u32*)(smem + KM_C);
  u32*  D    = (u32*)(smem + KM_D);
  float* deg = (float*)(smem + KM_C);   // overlays C after sort
  u32*  cnt  = (u32*)(smem + KM_D);     // overlays D after sort
  u32*  pr   = (u32*)(smem + KM_PR);
  u32*  hist = (u32*)(smem + KM_HIST);
  u32*  cum  = (u32*)(smem + KM_CUM);
  u32*  cur  = (u32*)(smem + KM_CUR);

  u32*  npG  = (u32*)(aggStash + (size_t)g * AGG_FRAME_U16);       // nodeP stash
  u16*  dvG  = aggStash + (size_t)g * AGG_FRAME_U16 + STASH_DINV_U16;

  // ---- bucket sort of keys = nid<<11 | idx (unique; bucket = key>>20) ----
  u32 k0 = ((u32)nidg[t] << 11) | (u32)t;
  u32 k1 = ((u32)nidg[t + 1024] << 11) | (u32)(t + 1024);
  D[t] = 0u; D[t + 1024] = 0u;
  __syncthreads();
  atomicAdd(&D[k0 >> 20], 1u);
  atomicAdd(&D[k1 >> 20], 1u);
  __syncthreads();
  // exclusive scan D -> C (bucket starts); aux in Btmp[0..1023]
  u32 c0 = D[2*t], c1 = D[2*t+1];
  Btmp[t] = c0 + c1;
  __syncthreads();
  for (int o = 1; o < 1024; o <<= 1) {
    u32 v = (t >= o) ? Btmp[t - o] : 0u;
    __syncthreads();
    Btmp[t] += v;
    __syncthreads();
  }
  {
    u32 base = (t == 0) ? 0u : Btmp[t - 1];
    C[2*t] = base; C[2*t+1] = base + c0;
  }
  // reset D as cursor
  D[t] = 0u; D[t + 1024] = 0u;
  __syncthreads();
  // scatter into Btmp (bucket regions; order within bucket arbitrary)
  {
    u32 b0 = k0 >> 20, b1 = k1 >> 20;
    Btmp[C[b0] + atomicAdd(&D[b0], 1u)] = k0;
    Btmp[C[b1] + atomicAdd(&D[b1], 1u)] = k1;
  }
  __syncthreads();   // D now holds final bucket counts again
  // exact in-bucket rank (unique keys) -> sorted A
  for (int p = t; p < NN; p += 1024) {
    u32 k = Btmp[p];
    u32 b = k >> 20;
    u32 s = C[b], e = s + D[b];
    u32 r = 0;
    for (u32 q = s; q < e; ++q) r += (Btmp[q] < k) ? 1u : 0u;
    A[s + r] = k;
  }
  __syncthreads();   // C/D dead -> deg/cnt overlay

  pr[2*t]   = (A[2*t]   & 2047u) << 16;   // graph node i's x-row = perm[i]
  pr[2*t+1] = (A[2*t+1] & 2047u) << 16;
  deg[t] = 1.0f; deg[t + 1024] = 1.0f;
  cnt[t] = 0u; cnt[t + 1024] = 0u;
  __syncthreads();

  // ---- degree (self-loop weight 1) + per-dst edge count ----
  for (int e = t; e < EE; e += 1024) {
    int d = eig[EE + e];
    atomicAdd(&deg[d], ewg[e]);
    atomicAdd(&cnt[d], 1u);
  }
  __syncthreads();
  {
    float d0 = rsqrtf(deg[2*t]), d1 = rsqrtf(deg[2*t+1]);
    dvG[2*t] = f2h(d0); dvG[2*t+1] = f2h(d1);   // f16 dinv by node (kScatter)
    deg[2*t] = d0; deg[2*t+1] = d1;             // f32 dinv by node
  }

  // ---- length histogram (256 buckets) ----
  if (t < 256) hist[t] = 0u;
  __syncthreads();
  for (int i = t; i < NN; i += 1024) {
    u32 L = cnt[i];
    atomicAdd(&hist[L < 255u ? L : 255u], 1u);
  }
  __syncthreads();
  if (t < 256) cum[t] = hist[t];
  __syncthreads();
  for (int o = 1; o < 256; o <<= 1) {
    u32 v = 0u;
    if (t < 256 && t >= o) v = cum[t - o];
    __syncthreads();
    if (t < 256) cum[t] += v;
    __syncthreads();
  }
  if (t < 256) cur[t] = (u32)NN - cum[t];   // bucket start (desc order)
  __syncthreads();
  if (t < 256) hist[t] = cur[t];            // scan buffer for off
  __syncthreads();
  for (int o = 1; o < 256; o <<= 1) {
    u32 v = 0u;
    if (t < 256 && t >= o) v = hist[t - o];
    __syncthreads();
    if (t < 256) hist[t] += v;
    __syncthreads();
  }
  if (t < 256) offG[(size_t)g * 256 + t] = hist[t] - cur[t];   // JDS offsets
  __syncthreads();

  // ---- rank assignment (desc length); export metaR + f32 dv2 by rank ----
  for (int i = t; i < NN; i += 1024) {
    u32 L = cnt[i];
    u32 b = L < 255u ? L : 255u;
    u32 r = atomicAdd(&cur[b], 1u);
    pr[i] |= r;
    metaR[(size_t)g * NN + r] = (pr[i] & 0xFFFF0000u) | (L & 0xFFFFu);
    float dv = deg[i];                       // f32 dinv
    dv2R[(size_t)g * NN + r] = dv * dv;
  }
  __syncthreads();
  // export nodeP (perm<<16|rank), coalesced
  npG[2*t]   = pr[2*t];
  npG[2*t+1] = pr[2*t+1];

  // ---- block 0: fold in W-prep ----
  if (g == 0) {
    for (int i = t; i < 4096; i += 1024) {
      int f = i >> 6, k = i & 63;
      W2bT[i] = f2bf(W2[k * 64 + f]);
    }
    if (t < 512) {
      int f = t & 63;
      float sc = g1[f] * rsqrtf(v1[f] + EPS);
      W1f[t] = W1[t] * sc;
    }
    if (t < 64) {
      float sc2 = g2[t] * rsqrtf(v2[t] + EPS);
      scG[t] = sc2;
      tcG[t] = (b2[t] - m2[t]) * sc2 + be2[t];
      float sc1 = g1[t] * rsqrtf(v1[t] + EPS);
      t1f[t] = (b1[t] - m1[t]) * sc1 + be1[t];
    }
  }
}

// =========================================================================
// kScatter: counting-sort edges into JDS rec in LDS; coalesced stream-out.
//   Reads nodeP/dinvN from the agg2-region stash (written by kMeta).
// =========================================================================
#define KS_REC  0        // u32[32768] = 131072
#define KS_CNT  131072   // u32[2048]
#define KS_PR   139264   // u32[2048]
#define KS_DINV 147456   // u16[2048]
#define KS_OFF  151552   // u32[256]
#define KS_LDS  152576

__global__ __launch_bounds__(1024) void kScatter(
    const int* __restrict__ ei, const float* __restrict__ ew,
    const u32* __restrict__ offG, const u16* __restrict__ aggStash,
    u32* __restrict__ recG)
{
  extern __shared__ unsigned char smem[];
  const int g = blockIdx.x, t = threadIdx.x;
  const int*   eig = ei + (size_t)g * 2 * EE;
  const float* ewg = ew + (size_t)g * EE;

  u32* rec   = (u32*)(smem + KS_REC);
  u32* cnt   = (u32*)(smem + KS_CNT);
  u32* prL   = (u32*)(smem + KS_PR);
  u16* dinvL = (u16*)(smem + KS_DINV);
  u32* off   = (u32*)(smem + KS_OFF);

  const u32* npG = (const u32*)(aggStash + (size_t)g * AGG_FRAME_U16);
  const u16* dvG = aggStash + (size_t)g * AGG_FRAME_U16 + STASH_DINV_U16;

  prL[2*t] = npG[2*t]; prL[2*t+1] = npG[2*t+1];
  dinvL[2*t] = dvG[2*t]; dinvL[2*t+1] = dvG[2*t+1];
  cnt[t] = 0u; cnt[t + 1024] = 0u;
  if (t < 256) off[t] = offG[(size_t)g * 256 + t];
  __syncthreads();

  for (int e = t; e < EE; e += 1024) {
    int s = eig[e], d = eig[EE + e];
    float nrm = h2f(dinvL[s]) * ewg[e] * h2f(dinvL[d]);
    u32 k = atomicAdd(&cnt[d], 1u);
    u32 pos = off[k] + (prL[d] & 0xFFFFu);
    rec[pos] = (prL[s] & 0xFFFF0000u) | (u32)f2h(nrm);   // src in ORIG x-row space
  }
  __syncthreads();

  uint4* rg = (uint4*)(recG + (size_t)g * EE);
  const uint4* rl = (const uint4*)rec;
  for (int i = t; i < EE / 4; i += 1024) rg[i] = rl[i];
}

// =========================================================================
// kFuse v9: thread-per-rank JDS walks; h1 f16[2048][16] in LDS (64KB,
//   shared with phase-A xs f32[2048][8]); 4 passes x 16 feats.
//   LDS 67.25KB -> 2 blocks/CU = 32 waves.  Phase C 1-wide + prefetch-1.
// =========================================================================
#define KF_H1   0        // A: xs f32[2048][8] (64KB); B/C: h1 f16[2048][16] (64KB)
#define KF_W1   65536    // f32[512]
#define KF_T1   67584    // f32[64]
#define KF_OFF  67840    // u32[256]
#define KF_LDS  68864

__global__ __launch_bounds__(1024) void kFuse(
    const float* __restrict__ x, const u32* __restrict__ recG,
    const u32* __restrict__ metaR, const float* __restrict__ dv2R,
    const u32* __restrict__ offG,
    const float* __restrict__ W1f, const float* __restrict__ t1f,
    u16* __restrict__ aggOut)
{
  extern __shared__ unsigned char smem[];
  u16*  h1   = (u16*)smem;                    // phases B/C: [2048][16] f16, 32B rows
  float* W1s = (float*)(smem + KF_W1);
  float* t1s = (float*)(smem + KF_T1);
  u32*  offL = (u32*)(smem + KF_OFF);
  const int g = blockIdx.x, t = threadIdx.x;
  const u32* recf = recG + (size_t)g * EE;

  // stage x rows (orig order, coalesced) + constants
  {
    const float4* xg = (const float4*)(x + (size_t)g * NN * 8);
    for (int i = t; i < NN * 2; i += 1024) ((float4*)smem)[i] = xg[i];
  }
  if (t < 512) W1s[t] = W1f[t];
  if (t < 64) t1s[t] = t1f[t];
  if (t >= 512 && t < 768) offL[t - 512] = offG[(size_t)g * 256 + (t - 512)];

  // per-rank meta + f32 dv2 (both rank-major, coalesced)
  u32 origA[2], lenA[2]; float dvA[2];
  #pragma unroll
  for (int it = 0; it < 2; ++it) {
    u32 r = (u32)(it * 1024 + t);
    u32 m = metaR[(size_t)g * NN + r];
    origA[it] = m >> 16; lenA[it] = m & 0xFFFFu;
    dvA[it] = dv2R[(size_t)g * NN + r];
  }
  __syncthreads();

  // ---- phase A: walk-1 in 8-dim x space, agg stays in registers ----
  float agg[2][8];
#define P1(RC) { u32 rc_ = (RC); u32 s_ = rc_ >> 16; \
    float nm_ = h2f((u16)(rc_ & 0xFFFFu)); \
    const float4* xp_ = (const float4*)(smem + (size_t)s_ * 32); \
    float4 a_ = xp_[0], b_ = xp_[1]; \
    ac0 += nm_*a_.x; ac1 += nm_*a_.y; ac2 += nm_*a_.z; ac3 += nm_*a_.w; \
    ac4 += nm_*b_.x; ac5 += nm_*b_.y; ac6 += nm_*b_.z; ac7 += nm_*b_.w; }
  #pragma unroll
  for (int it = 0; it < 2; ++it) {
    u32 r = (u32)(it * 1024 + t);
    float ac0=0,ac1=0,ac2=0,ac3=0,ac4=0,ac5=0,ac6=0,ac7=0;
    int len = (int)lenA[it];
    int j = 0;
    for (; j + 4 <= len; j += 4) {       // JDS: lane-contiguous rec reads
      u32 o0 = offL[j], o1 = offL[j+1], o2 = offL[j+2], o3 = offL[j+3];
      u32 q0 = recf[o0 + r], q1 = recf[o1 + r], q2 = recf[o2 + r], q3 = recf[o3 + r];
      P1(q0) P1(q1) P1(q2) P1(q3)
    }
    for (; j < len; ++j) { P1(recf[offL[j] + r]) }
    {  // self-loop (dv = dinv^2)
      const float4* xd = (const float4*)(smem + (size_t)origA[it] * 32);
      float4 a = xd[0], b = xd[1];
      float dv = dvA[it];
      ac0 += dv*a.x; ac1 += dv*a.y; ac2 += dv*a.z; ac3 += dv*a.w;
      ac4 += dv*b.x; ac5 += dv*b.y; ac6 += dv*b.z; ac7 += dv*b.w;
    }
    agg[it][0]=ac0; agg[it][1]=ac1; agg[it][2]=ac2; agg[it][3]=ac3;
    agg[it][4]=ac4; agg[it][5]=ac5; agg[it][6]=ac6; agg[it][7]=ac7;
  }
#undef P1

  // ---- 4 passes x 16 features ----
  for (int p = 0; p < 4; ++p) {
    __syncthreads();   // pass 0: xs dead; later: previous h1 readers done

    // phase B: h1 slice (feats p*16..p*16+15) from registers, f16, swizzled
    #pragma unroll
    for (int it = 0; it < 2; ++it) {
      float z[16];
      #pragma unroll
      for (int f = 0; f < 16; ++f) z[f] = t1s[p * 16 + f];
      #pragma unroll
      for (int k = 0; k < 8; ++k) {
        float fk = agg[it][k];
        const float4* wr = (const float4*)(W1s + k * 64 + p * 16);
        #pragma unroll
        for (int q = 0; q < 4; ++q) {
          float4 w = wr[q];
          z[4*q]   += fk * w.x; z[4*q+1] += fk * w.y;
          z[4*q+2] += fk * w.z; z[4*q+3] += fk * w.w;
        }
      }
      u32 orig = origA[it];
      u32 sw = (orig >> 2) & 1u;
      uint4* hp = (uint4*)(h1 + (size_t)orig * 16);
      #pragma unroll
      for (int u = 0; u < 2; ++u) {
        int b = u * 8;
        uint4 v = make_uint4(
          pack2h(fmaxf(z[b],   0.f), fmaxf(z[b+1], 0.f)),
          pack2h(fmaxf(z[b+2], 0.f), fmaxf(z[b+3], 0.f)),
          pack2h(fmaxf(z[b+4], 0.f), fmaxf(z[b+5], 0.f)),
          pack2h(fmaxf(z[b+6], 0.f), fmaxf(z[b+7], 0.f)));
        hp[u ^ sw] = v;
      }
    }
    __syncthreads();

    // phase C: walk-2, 16 feats, acc in regs; 1-wide + prefetch-1
#define ROWACC(SRC, NM, OP) { u32 s_ = (SRC); float nm_ = (NM); \
    u32 sw_ = (s_ >> 2) & 1u; \
    const uint4* rp_ = (const uint4*)(h1 + (size_t)s_ * 16); \
    _Pragma("unroll") \
    for (int u = 0; u < 2; ++u) { \
      uint4 w_ = rp_[u ^ sw_]; \
      int b_ = u * 8; \
      acc[b_+0] OP nm_ * h2f((u16)(w_.x & 0xFFFFu)); \
      acc[b_+1] OP nm_ * h2f((u16)(w_.x >> 16)); \
      acc[b_+2] OP nm_ * h2f((u16)(w_.y & 0xFFFFu)); \
      acc[b_+3] OP nm_ * h2f((u16)(w_.y >> 16)); \
      acc[b_+4] OP nm_ * h2f((u16)(w_.z & 0xFFFFu)); \
      acc[b_+5] OP nm_ * h2f((u16)(w_.z >> 16)); \
      acc[b_+6] OP nm_ * h2f((u16)(w_.w & 0xFFFFu)); \
      acc[b_+7] OP nm_ * h2f((u16)(w_.w >> 16)); \
    } }

    for (int it = 0; it < 2; ++it) {
      u32 r = (u32)(it * 1024 + t);
      float acc[16];
      ROWACC(origA[it], dvA[it], =)      // self-loop initializes acc
      int len = (int)lenA[it];
      if (len > 0) {
        u32 qn = recf[offL[0] + r];      // prefetch-1
        int j = 0;
        for (; j < len - 1; ++j) {
          u32 q = qn;
          qn = recf[offL[j + 1] + r];
          ROWACC(q >> 16, h2f((u16)(q & 0xFFFFu)), +=)
        }
        ROWACC(qn >> 16, h2f((u16)(qn & 0xFFFFu)), +=)
      }
      // pass p -> unit-planes p*2, p*2+1 (feats p*16+u*8..+7), 16B/lane
      #pragma unroll
      for (int u = 0; u < 2; ++u) {
        int b = u * 8;
        uint4 o = make_uint4(
          pack2bf(acc[b],   acc[b+1]), pack2bf(acc[b+2], acc[b+3]),
          pack2bf(acc[b+4], acc[b+5]), pack2bf(acc[b+6], acc[b+7]));
        *((uint4*)aggOut + ((size_t)(g * 8 + p * 2 + u)) * NN + r) = o;
      }
    }
#undef ROWACC
  }
}

// =========================================================================
// kB: MFMA GEMM  C = agg2[2048x64](bf16, 8 unit-planes) @ W2(bf16), fused
//     BN+ReLU+mean.  A/B frags share one k-slot bijection.
// =========================================================================
__global__ __launch_bounds__(512) void kB(
    const u16* __restrict__ agg, const u16* __restrict__ W2bT,
    const float* __restrict__ scG, const float* __restrict__ tcG,
    float* __restrict__ frames)
{
  __shared__ u16 W2s[4096];          // bf16 [f=64][k=64]
  __shared__ float part[8][64];
  const int g = blockIdx.x, tid = threadIdx.x;
  const int l = tid & 63, w = tid >> 6;
  const int lc = l & 15, lg = l >> 4;          // frag col / k-group

  ((uint4*)W2s)[tid] = ((const uint4*)W2bT)[tid];
  __syncthreads();

  short8 bfr[4][2];
  float scv[4], tcv[4];
  #pragma unroll
  for (int ct = 0; ct < 4; ++ct) {
    #pragma unroll
    for (int kt = 0; kt < 2; ++kt)
      bfr[ct][kt] = *(const short8*)(W2s + (ct * 16 + lc) * 64 + kt * 32 + lg * 8);
    scv[ct] = scG[ct * 16 + lc];
    tcv[ct] = tcG[ct * 16 + lc];
  }

  const u16* base = agg + (size_t)g * (8 * NN * 8);   // 8 unit-planes x NN x 8 u16
  float fs0 = 0.f, fs1 = 0.f, fs2 = 0.f, fs3 = 0.f;

  for (int rti = 0; rti < 16; ++rti) {
    int arow = (w * 16 + rti) * 16 + lc;
    short8 a0 = *(const short8*)(base + ((size_t)(0 * 4 + lg) * NN + arow) * 8);
    short8 a1 = *(const short8*)(base + ((size_t)(1 * 4 + lg) * NN + arow) * 8);
#define CTILE(CT, FS) { \
    f32x4 acc = {0.f, 0.f, 0.f, 0.f}; \
    acc = __builtin_amdgcn_mfma_f32_16x16x32_bf16(a0, bfr[CT][0], acc, 0, 0, 0); \
    acc = __builtin_amdgcn_mfma_f32_16x16x32_bf16(a1, bfr[CT][1], acc, 0, 0, 0); \
    float s_ = fmaxf(acc[0] * scv[CT] + tcv[CT], 0.f) \
             + fmaxf(acc[1] * scv[CT] + tcv[CT], 0.f) \
             + fmaxf(acc[2] * scv[CT] + tcv[CT], 0.f) \
             + fmaxf(acc[3] * scv[CT] + tcv[CT], 0.f); \
    s_ += __shfl_xor(s_, 16); \
    s_ += __shfl_xor(s_, 32); \
    FS += s_; }
    CTILE(0, fs0) CTILE(1, fs1) CTILE(2, fs2) CTILE(3, fs3)
#undef CTILE
  }
  if (l < 16) {
    part[w][ 0 + l] = fs0;
    part[w][16 + l] = fs1;
    part[w][32 + l] = fs2;
    part[w][48 + l] = fs3;
  }
  __syncthreads();
  if (tid < 64) {
    float s = 0.f;
    #pragma unroll
    for (int q = 0; q < 8; ++q) s += part[q][tid];
    frames[g * 64 + tid] = s * (1.0f / 2048.0f);
  }
}

// =========================================================================
// kC: GRU over T=30 + classifier; one block per batch element
// =========================================================================
__global__ __launch_bounds__(384, 2) void kC(
    const float* __restrict__ frames,
    const float* __restrict__ Wih, const float* __restrict__ Whh,
    const float* __restrict__ bih, const float* __restrict__ bhh,
    const float* __restrict__ Wc1, const float* __restrict__ bc1,
    const float* __restrict__ Wc2, const float* __restrict__ bc2,
    float* __restrict__ out)
{
  const int b = blockIdx.x;
  const int j = threadIdx.x;     // 384 = 3*TEMP gate rows
  __shared__ float xt[64], h[128], GI[384], GH[384], hid[64];
  float wih[64], whh[128];
  const float4* wi4 = (const float4*)(Wih + (size_t)j * 64);
  #pragma unroll
  for (int q = 0; q < 16; ++q) { float4 v = wi4[q]; wih[4*q]=v.x; wih[4*q+1]=v.y; wih[4*q+2]=v.z; wih[4*q+3]=v.w; }
  const float4* wh4 = (const float4*)(Whh + (size_t)j * 128);
  #pragma unroll
  for (int q = 0; q < 32; ++q) { float4 v = wh4[q]; whh[4*q]=v.x; whh[4*q+1]=v.y; whh[4*q+2]=v.z; whh[4*q+3]=v.w; }
  float bi = bih[j], bh = bhh[j];
  if (j < 128) h[j] = 0.f;
  __syncthreads();
  for (int t = 0; t < T_; ++t) {
    if (j < 64) xt[j] = frames[((size_t)b * T_ + t) * 64 + j];
    __syncthreads();
    float gi = bi, gh = bh;
    #pragma unroll
    for (int k = 0; k < 64; ++k) gi += xt[k] * wih[k];
    #pragma unroll
    for (int k = 0; k < 128; ++k) gh += h[k] * whh[k];
    GI[j] = gi; GH[j] = gh;
    __syncthreads();
    if (j < 128) {
      float r = 1.f / (1.f + __expf(-(GI[j] + GH[j])));
      float z = 1.f / (1.f + __expf(-(GI[128 + j] + GH[128 + j])));
      float n = tanhf(GI[256 + j] + r * GH[256 + j]);
      h[j] = (1.f - z) * n + z * h[j];
    }
    __syncthreads();
  }
  if (j < 64) {
    float a = bc1[j];
    #pragma unroll 4
    for (int k = 0; k < 128; ++k) a += h[k] * Wc1[k * 64 + j];
    hid[j] = fmaxf(a, 0.f);
  }
  __syncthreads();
  if (j < 2) {
    float o = bc2[j];
    #pragma unroll
    for (int k = 0; k < 64; ++k) o += hid[k] * Wc2[k * 2 + j];
    out[b * 2 + j] = o;
  }
}

// ---------- launch ----------
extern "C" void kernel_launch(void* const* d_in, const int* in_sizes, int n_in,
                              void* d_out, int out_size, void* d_ws, size_t ws_size,
                              hipStream_t stream) {
  const float* x   = (const float*)d_in[0];
  const int*   ei  = (const int*)d_in[1];
  const float* ew  = (const float*)d_in[2];
  const int*   nid = (const int*)d_in[3];
  const float* W1  = (const float*)d_in[4];
  const float* b1  = (const float*)d_in[5];
  const float* W2  = (const float*)d_in[6];
  const float* b2  = (const float*)d_in[7];
  const float* g1  = (const float*)d_in[8];
  const float* be1 = (const float*)d_in[9];
  const float* m1  = (const float*)d_in[10];
  const float* v1  = (const float*)d_in[11];
  const float* g2  = (const float*)d_in[12];
  const float* be2 = (const float*)d_in[13];
  const float* m2  = (const float*)d_in[14];
  const float* v2  = (const float*)d_in[15];
  const float* Wih = (const float*)d_in[16];
  const float* Whh = (const float*)d_in[17];
  const float* bih = (const float*)d_in[18];
  const float* bhh = (const float*)d_in[19];
  const float* Wc1 = (const float*)d_in[20];
  const float* bc1 = (const float*)d_in[21];
  const float* Wc2 = (const float*)d_in[22];
  const float* bc2 = (const float*)d_in[23];
  float* out = (float*)d_out;

  // workspace layout (bytes), total ~197.2MB (unchanged)
  const size_t REC_OFF   = 0;                    // 62,914,560
  const size_t PL_OFF    = 62914560;             // agg2 8 unit-planes bf16 (+ per-frame stash)
  const size_t META_OFF  = 188743680;            // metaR u32[480*2048]
  const size_t DV2_OFF   = 192675840;            // dv2R f32[480*2048]
  const size_t OFF_OFF   = 196608000;            // u32[480*256]
  const size_t PREP_OFF  = 197099520;            // W2bT 8192 | scG 256 | tcG 256 | W1f 2048 | t1f 256
  const size_t FR_OFF    = 197110528;            // 122,880
  if (ws_size < (size_t)197233408) return;

  u32*   rec   = (u32*)((char*)d_ws + REC_OFF);
  u16*   agg2  = (u16*)((char*)d_ws + PL_OFF);
  u32*   metaR = (u32*)((char*)d_ws + META_OFF);
  float* dv2R  = (float*)((char*)d_ws + DV2_OFF);
  u32*   offG  = (u32*)((char*)d_ws + OFF_OFF);
  u16*   W2bT  = (u16*)((char*)d_ws + PREP_OFF);
  float* scG   = (float*)((char*)d_ws + PREP_OFF + 8192);
  float* tcG   = (float*)((char*)d_ws + PREP_OFF + 8448);
  float* W1f   = (float*)((char*)d_ws + PREP_OFF + 8704);
  float* t1f   = (float*)((char*)d_ws + PREP_OFF + 10752);
  float* frm   = (float*)((char*)d_ws + FR_OFF);

  hipFuncSetAttribute((const void*)kMeta,    hipFuncAttributeMaxDynamicSharedMemorySize, KM_LDS);
  hipFuncSetAttribute((const void*)kScatter, hipFuncAttributeMaxDynamicSharedMemorySize, KS_LDS);
  hipFuncSetAttribute((const void*)kFuse,    hipFuncAttributeMaxDynamicSharedMemorySize, KF_LDS);

  kMeta<<<NF, 1024, KM_LDS, stream>>>(ei, ew, nid, metaR, dv2R, offG, agg2,
                                      W2, b2, g2, be2, m2, v2,
                                      W1, b1, g1, be1, m1, v1,
                                      W2bT, scG, tcG, W1f, t1f);
  kScatter<<<NF, 1024, KS_LDS, stream>>>(ei, ew, offG, agg2, rec);
  kFuse<<<NF, 1024, KF_LDS, stream>>>(x, rec, metaR, dv2R, offG, W1f, t1f, agg2);
  kB<<<NF, 512, 0, stream>>>(agg2, W2bT, scG, tcG, frm);
  kC<<<B_, 384, 0, stream>>>(frm, Wih, Whh, bih, bhh, Wc1, bc1, Wc2, bc2, out);
}